// Round 1
// baseline (221.935 us; speedup 1.0000x reference)
//
#include <hip/hip_runtime.h>
#include <math.h>

#define IN_DIM 256
#define HD 256
#define HEADS 4
#define OUT_D 64
#define EDGE_DIM 32
#define NEG_SLOPE 0.2f

// ---------------- detect int64 vs int32 edge_index ----------------
__global__ void detect_kernel(const int* __restrict__ ei, int* __restrict__ flag) {
    __shared__ int anynz;
    if (threadIdx.x == 0) anynz = 0;
    __syncthreads();
    int v = ei[2 * threadIdx.x + 1];  // high word if int64, else src of odd edges
    if (v != 0) atomicOr(&anynz, 1);
    __syncthreads();
    if (threadIdx.x == 0) *flag = (anynz == 0) ? 1 : 0;
}

__device__ __forceinline__ void load_edge(const int* ei, int e, int E, int n, int is64,
                                          int& s, int& d) {
    if (e < E) {
        if (is64) { s = ei[2 * e]; d = ei[2 * E + 2 * e]; }
        else      { s = ei[e];     d = ei[E + e]; }
    } else {
        s = d = e - E;  // self loop
    }
}

// ---------------- zero deg ----------------
__global__ void zero_kernel(int* __restrict__ deg, int n) {
    int i = blockIdx.x * blockDim.x + threadIdx.x;
    if (i < n) deg[i] = 0;
}

// ---------------- w_eff[h][k] = sum_d lin_edge_W[(h*64+d)*32+k] * att_edge[h*64+d] ----------------
__global__ void weff_kernel(const float* __restrict__ lew, const float* __restrict__ ae,
                            float* __restrict__ weff) {
    int t = threadIdx.x;  // 128 threads
    int h = t >> 5, k = t & 31;
    float s = 0.f;
#pragma unroll 8
    for (int d = 0; d < 64; ++d) s += lew[(h * 64 + d) * 32 + k] * ae[h * 64 + d];
    weff[t] = s;
}

// ---------------- x_proj = x @ W^T  (x: [n,256], W: [256,256] row-major [c][k]) ----------------
#define BM 64
#define BKT 16
__global__ __launch_bounds__(256) void proj_kernel(const float* __restrict__ x,
                                                   const float* __restrict__ W,
                                                   float* __restrict__ xp, int n) {
    __shared__ float xs[BM][BKT + 1];
    __shared__ float wsm[BKT][256];
    int tid = threadIdx.x;
    int tx = tid & 15;   // col quad group
    int ty = tid >> 4;   // node group
    int n0 = blockIdx.x * BM;

    float4 acc[4][4];
#pragma unroll
    for (int i = 0; i < 4; ++i)
#pragma unroll
        for (int j = 0; j < 4; ++j) acc[i][j] = make_float4(0.f, 0.f, 0.f, 0.f);

    for (int k0 = 0; k0 < IN_DIM; k0 += BKT) {
        // stage x tile [64][16]
        int m = tid >> 2, j = tid & 3;
        int nn = n0 + m;
        float4 xv = make_float4(0.f, 0.f, 0.f, 0.f);
        if (nn < n) xv = *(const float4*)&x[(size_t)nn * IN_DIM + k0 + 4 * j];
        xs[m][4 * j + 0] = xv.x;
        xs[m][4 * j + 1] = xv.y;
        xs[m][4 * j + 2] = xv.z;
        xs[m][4 * j + 3] = xv.w;
        // stage W tile transposed: wsm[kk][c], c = tid
        float4 wv[4];
#pragma unroll
        for (int j2 = 0; j2 < 4; ++j2)
            wv[j2] = *(const float4*)&W[(size_t)tid * IN_DIM + k0 + 4 * j2];
#pragma unroll
        for (int j2 = 0; j2 < 4; ++j2) {
            wsm[4 * j2 + 0][tid] = wv[j2].x;
            wsm[4 * j2 + 1][tid] = wv[j2].y;
            wsm[4 * j2 + 2][tid] = wv[j2].z;
            wsm[4 * j2 + 3][tid] = wv[j2].w;
        }
        __syncthreads();
#pragma unroll
        for (int kk = 0; kk < BKT; ++kk) {
            float a_[4];
#pragma unroll
            for (int i = 0; i < 4; ++i) a_[i] = xs[ty * 4 + i][kk];
            float4 b_[4];
#pragma unroll
            for (int jj = 0; jj < 4; ++jj)
                b_[jj] = *(const float4*)&wsm[kk][jj * 64 + tx * 4];
#pragma unroll
            for (int i = 0; i < 4; ++i)
#pragma unroll
                for (int jj = 0; jj < 4; ++jj) {
                    acc[i][jj].x += a_[i] * b_[jj].x;
                    acc[i][jj].y += a_[i] * b_[jj].y;
                    acc[i][jj].z += a_[i] * b_[jj].z;
                    acc[i][jj].w += a_[i] * b_[jj].w;
                }
        }
        __syncthreads();
    }
#pragma unroll
    for (int i = 0; i < 4; ++i) {
        int nn = n0 + ty * 4 + i;
        if (nn < n) {
#pragma unroll
            for (int jj = 0; jj < 4; ++jj)
                *(float4*)&xp[(size_t)nn * HD + jj * 64 + tx * 4] = acc[i][jj];
        }
    }
}

// ---------------- s_src/s_dst per node (wave per node) ----------------
__global__ __launch_bounds__(256) void sscore_kernel(const float* __restrict__ xp,
                                                     const float* __restrict__ asrc,
                                                     const float* __restrict__ adst,
                                                     float* __restrict__ s_src,
                                                     float* __restrict__ s_dst, int n) {
    int wid = (blockIdx.x * blockDim.x + threadIdx.x) >> 6;
    int lane = threadIdx.x & 63;
    if (wid >= n) return;
    float4 xv = *(const float4*)&xp[(size_t)wid * HD + lane * 4];
    float4 as = *(const float4*)&asrc[lane * 4];
    float4 ad = *(const float4*)&adst[lane * 4];
    float ss = xv.x * as.x + xv.y * as.y + xv.z * as.z + xv.w * as.w;
    float sd = xv.x * ad.x + xv.y * ad.y + xv.z * ad.z + xv.w * ad.w;
#pragma unroll
    for (int m = 1; m < 16; m <<= 1) {
        ss += __shfl_xor(ss, m);
        sd += __shfl_xor(sd, m);
    }
    if ((lane & 15) == 0) {
        s_src[wid * 4 + (lane >> 4)] = ss;
        s_dst[wid * 4 + (lane >> 4)] = sd;
    }
}

// ---------------- per-edge scores + degree histogram ----------------
__global__ __launch_bounds__(256) void edge_kernel(const int* __restrict__ ei,
                                                   const float* __restrict__ ea,
                                                   const float* __restrict__ s_src,
                                                   const float* __restrict__ s_dst,
                                                   const float* __restrict__ weff,
                                                   const int* __restrict__ flag,
                                                   float* __restrict__ att,
                                                   int* __restrict__ deg, int E, int n) {
    __shared__ float we[128];
    if (threadIdx.x < 128) we[threadIdx.x] = weff[threadIdx.x];
    __syncthreads();
    int e = blockIdx.x * blockDim.x + threadIdx.x;
    int EP = E + n;
    if (e >= EP) return;
    int is64 = *flag;
    int s, d;
    load_edge(ei, e, E, n, is64, s, d);
    float4 vs = *(const float4*)&s_src[(size_t)s * 4];
    float4 vd = *(const float4*)&s_dst[(size_t)d * 4];
    float ed[4] = {0.f, 0.f, 0.f, 0.f};
    if (e < E) {
#pragma unroll
        for (int k = 0; k < EDGE_DIM; k += 4) {
            float4 v = *(const float4*)&ea[(size_t)e * EDGE_DIM + k];
#pragma unroll
            for (int h = 0; h < 4; ++h) {
                ed[h] += v.x * we[h * 32 + k + 0] + v.y * we[h * 32 + k + 1] +
                         v.z * we[h * 32 + k + 2] + v.w * we[h * 32 + k + 3];
            }
        }
    }
    float t0 = vs.x + vd.x + ed[0];
    float t1 = vs.y + vd.y + ed[1];
    float t2 = vs.z + vd.z + ed[2];
    float t3 = vs.w + vd.w + ed[3];
    float4 o;
    o.x = t0 >= 0.f ? t0 : NEG_SLOPE * t0;
    o.y = t1 >= 0.f ? t1 : NEG_SLOPE * t1;
    o.z = t2 >= 0.f ? t2 : NEG_SLOPE * t2;
    o.w = t3 >= 0.f ? t3 : NEG_SLOPE * t3;
    *(float4*)&att[(size_t)e * 4] = o;
    atomicAdd(&deg[d], 1);
}

// ---------------- single-block exclusive scan over deg ----------------
#define SCAN_T 1024
__global__ __launch_bounds__(SCAN_T) void scan_kernel(const int* __restrict__ deg,
                                                      int* __restrict__ rowptr,
                                                      int* __restrict__ cursor, int n) {
    __shared__ int sdata[SCAN_T];
    int t = threadIdx.x;
    int per = (n + SCAN_T - 1) / SCAN_T;
    int begin = t * per;
    int endi = begin + per;
    if (endi > n) endi = n;
    int s = 0;
    for (int i = begin; i < endi; ++i) s += deg[i];
    sdata[t] = s;
    __syncthreads();
    for (int off = 1; off < SCAN_T; off <<= 1) {
        int v = 0;
        if (t >= off) v = sdata[t - off];
        __syncthreads();
        sdata[t] += v;
        __syncthreads();
    }
    int run = (t == 0) ? 0 : sdata[t - 1];
    for (int i = begin; i < endi; ++i) {
        int dv = deg[i];
        rowptr[i] = run;
        cursor[i] = run;
        run += dv;
    }
    if (t == SCAN_T - 1) rowptr[n] = run;
}

// ---------------- scatter edges into CSR buckets ----------------
__global__ __launch_bounds__(256) void scatter_kernel(const int* __restrict__ ei,
                                                      const int* __restrict__ flag,
                                                      int* __restrict__ cursor,
                                                      int* __restrict__ ssrc,
                                                      int* __restrict__ seid, int E, int n) {
    int e = blockIdx.x * blockDim.x + threadIdx.x;
    int EP = E + n;
    if (e >= EP) return;
    int is64 = *flag;
    int s, d;
    load_edge(ei, e, E, n, is64, s, d);
    int pos = atomicAdd(&cursor[d], 1);
    ssrc[pos] = s;
    seid[pos] = e;
}

// ---------------- softmax + aggregation: one wave per node ----------------
__global__ __launch_bounds__(256) void agg_kernel(const int* __restrict__ rowptr,
                                                  const int* __restrict__ ssrc,
                                                  const int* __restrict__ seid,
                                                  const float* __restrict__ att,
                                                  const float* __restrict__ xp,
                                                  const float* __restrict__ bias,
                                                  float* __restrict__ out, int n) {
    int wid = (blockIdx.x * blockDim.x + threadIdx.x) >> 6;
    int lane = threadIdx.x & 63;
    if (wid >= n) return;
    int start = rowptr[wid];
    int end = rowptr[wid + 1];

    float m0 = -1e30f, m1 = -1e30f, m2 = -1e30f, m3 = -1e30f;
    for (int i = start + lane; i < end; i += 64) {
        float4 a = *(const float4*)&att[(size_t)seid[i] * 4];
        m0 = fmaxf(m0, a.x); m1 = fmaxf(m1, a.y);
        m2 = fmaxf(m2, a.z); m3 = fmaxf(m3, a.w);
    }
#pragma unroll
    for (int o = 1; o < 64; o <<= 1) {
        m0 = fmaxf(m0, __shfl_xor(m0, o));
        m1 = fmaxf(m1, __shfl_xor(m1, o));
        m2 = fmaxf(m2, __shfl_xor(m2, o));
        m3 = fmaxf(m3, __shfl_xor(m3, o));
    }
    float d0 = 0.f, d1 = 0.f, d2 = 0.f, d3 = 0.f;
    for (int i = start + lane; i < end; i += 64) {
        float4 a = *(const float4*)&att[(size_t)seid[i] * 4];
        d0 += expf(a.x - m0); d1 += expf(a.y - m1);
        d2 += expf(a.z - m2); d3 += expf(a.w - m3);
    }
#pragma unroll
    for (int o = 1; o < 64; o <<= 1) {
        d0 += __shfl_xor(d0, o);
        d1 += __shfl_xor(d1, o);
        d2 += __shfl_xor(d2, o);
        d3 += __shfl_xor(d3, o);
    }
    int h = lane >> 4;
    float mh = h == 0 ? m0 : (h == 1 ? m1 : (h == 2 ? m2 : m3));
    float dh = h == 0 ? d0 : (h == 1 ? d1 : (h == 2 ? d2 : d3));
    float invh = 1.f / (dh + 1e-12f);

    float4 acc = make_float4(0.f, 0.f, 0.f, 0.f);
    for (int i = start; i < end; ++i) {
        int s = ssrc[i];
        int e = seid[i];
        float av = att[(size_t)e * 4 + h];
        float alpha = expf(av - mh) * invh;
        float4 xv = *(const float4*)&xp[(size_t)s * HD + lane * 4];
        acc.x += alpha * xv.x;
        acc.y += alpha * xv.y;
        acc.z += alpha * xv.z;
        acc.w += alpha * xv.w;
    }
    float4 b = *(const float4*)&bias[lane * 4];
    acc.x += b.x; acc.y += b.y; acc.z += b.z; acc.w += b.w;
    *(float4*)&out[(size_t)wid * HD + lane * 4] = acc;
}

extern "C" void kernel_launch(void* const* d_in, const int* in_sizes, int n_in,
                              void* d_out, int out_size, void* d_ws, size_t ws_size,
                              hipStream_t stream) {
    const float* x        = (const float*)d_in[0];
    const int*   ei       = (const int*)d_in[1];
    const float* ea       = (const float*)d_in[2];
    const float* lin_W    = (const float*)d_in[3];
    const float* att_src  = (const float*)d_in[4];
    const float* att_dst  = (const float*)d_in[5];
    const float* lin_eW   = (const float*)d_in[6];
    const float* att_edge = (const float*)d_in[7];
    const float* bias     = (const float*)d_in[8];
    float* out = (float*)d_out;

    int n  = in_sizes[0] / IN_DIM;     // 20000
    int E  = in_sizes[2] / EDGE_DIM;   // 320000
    int EP = E + n;

    char* p = (char*)d_ws;
    auto alloc = [&](size_t bytes) {
        char* r = p;
        p += (bytes + 255) & ~(size_t)255;
        return r;
    };
    float* xp     = (float*)alloc((size_t)n * HD * 4);
    float* s_src  = (float*)alloc((size_t)n * 4 * 4);
    float* s_dst  = (float*)alloc((size_t)n * 4 * 4);
    float* att    = (float*)alloc((size_t)EP * 4 * 4);
    float* weff   = (float*)alloc(128 * 4);
    int*   deg    = (int*)alloc((size_t)n * 4);
    int*   rowptr = (int*)alloc((size_t)(n + 1) * 4);
    int*   cursor = (int*)alloc((size_t)n * 4);
    int*   ssrc   = (int*)alloc((size_t)EP * 4);
    int*   seid   = (int*)alloc((size_t)EP * 4);
    int*   flag   = (int*)alloc(4);

    detect_kernel<<<1, 256, 0, stream>>>(ei, flag);
    zero_kernel<<<(n + 255) / 256, 256, 0, stream>>>(deg, n);
    weff_kernel<<<1, 128, 0, stream>>>(lin_eW, att_edge, weff);
    proj_kernel<<<(n + BM - 1) / BM, 256, 0, stream>>>(x, lin_W, xp, n);
    sscore_kernel<<<(n + 3) / 4, 256, 0, stream>>>(xp, att_src, att_dst, s_src, s_dst, n);
    edge_kernel<<<(EP + 255) / 256, 256, 0, stream>>>(ei, ea, s_src, s_dst, weff, flag,
                                                      att, deg, E, n);
    scan_kernel<<<1, SCAN_T, 0, stream>>>(deg, rowptr, cursor, n);
    scatter_kernel<<<(EP + 255) / 256, 256, 0, stream>>>(ei, flag, cursor, ssrc, seid, E, n);
    agg_kernel<<<(n + 3) / 4, 256, 0, stream>>>(rowptr, ssrc, seid, att, xp, bias, out, n);
}

// Round 2
// 163.223 us; speedup vs baseline: 1.3597x; 1.3597x over previous
//
#include <hip/hip_runtime.h>
#include <math.h>

#define IN_DIM 256
#define HD 256
#define HEADS 4
#define EDGE_DIM 32
#define NEG_SLOPE 0.2f

typedef _Float16 f16x8 __attribute__((ext_vector_type(8)));
typedef _Float16 f16x4 __attribute__((ext_vector_type(4)));
typedef float f32x4 __attribute__((ext_vector_type(4)));

__device__ __forceinline__ void load_edge(const int* ei, int e, int E, int n, int is64,
                                          int& s, int& d) {
    if (e < E) {
        if (is64) { s = ei[2 * e]; d = ei[2 * E + 2 * e]; }
        else      { s = ei[e];     d = ei[E + e]; }
    } else {
        s = d = e - E;  // self loop
    }
}

// ---------- fused prep: weff (block 0), int64-detect (block 1), zero deg (blocks 2..) ----------
__global__ __launch_bounds__(256) void prep_kernel(const int* __restrict__ ei,
                                                   const float* __restrict__ lew,
                                                   const float* __restrict__ ae,
                                                   float* __restrict__ weff,
                                                   int* __restrict__ deg,
                                                   int* __restrict__ flag, int n) {
    int b = blockIdx.x;
    if (b == 0) {
        int t = threadIdx.x;
        if (t < 128) {
            int h = t >> 5, k = t & 31;
            float s = 0.f;
#pragma unroll 8
            for (int d = 0; d < 64; ++d) s += lew[(h * 64 + d) * 32 + k] * ae[h * 64 + d];
            weff[t] = s;
        }
    } else if (b == 1) {
        __shared__ int anynz;
        if (threadIdx.x == 0) anynz = 0;
        __syncthreads();
        int v = ei[2 * threadIdx.x + 1];  // high word if int64
        if (v != 0) atomicOr(&anynz, 1);
        __syncthreads();
        if (threadIdx.x == 0) *flag = (anynz == 0) ? 1 : 0;
    } else {
        int i = (b - 2) * 256 + threadIdx.x;
        if (i < n) deg[i] = 0;
    }
}

// ---------- x_proj (fp16) = fp16(x) @ fp16(W)^T via MFMA, 64 rows x 256 cols per block ----------
__global__ __launch_bounds__(256) void proj_kernel(const float* __restrict__ x,
                                                   const float* __restrict__ W,
                                                   _Float16* __restrict__ xph, int n) {
    int tid = threadIdx.x;
    int lane = tid & 63;
    int w = tid >> 6;            // wave id 0..3 -> col group
    int m0 = blockIdx.x * 64;
    int c0 = w * 64;
    int r = lane & 15;
    int kq = lane >> 4;          // 0..3

    f32x4 acc[4][4];
#pragma unroll
    for (int i = 0; i < 4; ++i)
#pragma unroll
        for (int j = 0; j < 4; ++j) acc[i][j] = (f32x4){0.f, 0.f, 0.f, 0.f};

    for (int k0 = 0; k0 < IN_DIM; k0 += 32) {
        int kk = k0 + kq * 8;
        f16x8 a[4], bfr[4];
#pragma unroll
        for (int mi = 0; mi < 4; ++mi) {
            int row = m0 + mi * 16 + r;
            f16x8 av = {0, 0, 0, 0, 0, 0, 0, 0};
            if (row < n) {
                const float* p = &x[(size_t)row * IN_DIM + kk];
                float4 lo = *(const float4*)p;
                float4 hi = *(const float4*)(p + 4);
                av[0] = (_Float16)lo.x; av[1] = (_Float16)lo.y;
                av[2] = (_Float16)lo.z; av[3] = (_Float16)lo.w;
                av[4] = (_Float16)hi.x; av[5] = (_Float16)hi.y;
                av[6] = (_Float16)hi.z; av[7] = (_Float16)hi.w;
            }
            a[mi] = av;
        }
#pragma unroll
        for (int ci = 0; ci < 4; ++ci) {
            int col = c0 + ci * 16 + r;
            const float* p = &W[(size_t)col * IN_DIM + kk];
            float4 lo = *(const float4*)p;
            float4 hi = *(const float4*)(p + 4);
            f16x8 bv;
            bv[0] = (_Float16)lo.x; bv[1] = (_Float16)lo.y;
            bv[2] = (_Float16)lo.z; bv[3] = (_Float16)lo.w;
            bv[4] = (_Float16)hi.x; bv[5] = (_Float16)hi.y;
            bv[6] = (_Float16)hi.z; bv[7] = (_Float16)hi.w;
            bfr[ci] = bv;
        }
#pragma unroll
        for (int mi = 0; mi < 4; ++mi)
#pragma unroll
            for (int ci = 0; ci < 4; ++ci)
                acc[mi][ci] = __builtin_amdgcn_mfma_f32_16x16x32_f16(a[mi], bfr[ci],
                                                                     acc[mi][ci], 0, 0, 0);
    }
    // C/D layout: col = lane&15, row = (lane>>4)*4 + j   [m89-verified]
#pragma unroll
    for (int mi = 0; mi < 4; ++mi) {
#pragma unroll
        for (int j = 0; j < 4; ++j) {
            int row = m0 + mi * 16 + kq * 4 + j;
            if (row < n) {
#pragma unroll
                for (int ci = 0; ci < 4; ++ci) {
                    int col = c0 + ci * 16 + r;
                    xph[(size_t)row * HD + col] = (_Float16)acc[mi][ci][j];
                }
            }
        }
    }
}

// ---------- s_src/s_dst per node (wave per node) ----------
__global__ __launch_bounds__(256) void sscore_kernel(const _Float16* __restrict__ xph,
                                                     const float* __restrict__ asrc,
                                                     const float* __restrict__ adst,
                                                     float* __restrict__ s_src,
                                                     float* __restrict__ s_dst, int n) {
    int wid = (blockIdx.x * blockDim.x + threadIdx.x) >> 6;
    int lane = threadIdx.x & 63;
    if (wid >= n) return;
    f16x4 xv = *(const f16x4*)&xph[(size_t)wid * HD + lane * 4];
    float4 as = *(const float4*)&asrc[lane * 4];
    float4 ad = *(const float4*)&adst[lane * 4];
    float x0 = (float)xv[0], x1 = (float)xv[1], x2 = (float)xv[2], x3 = (float)xv[3];
    float ss = x0 * as.x + x1 * as.y + x2 * as.z + x3 * as.w;
    float sd = x0 * ad.x + x1 * ad.y + x2 * ad.z + x3 * ad.w;
#pragma unroll
    for (int m = 1; m < 16; m <<= 1) {
        ss += __shfl_xor(ss, m);
        sd += __shfl_xor(sd, m);
    }
    if ((lane & 15) == 0) {
        s_src[wid * 4 + (lane >> 4)] = ss;
        s_dst[wid * 4 + (lane >> 4)] = sd;
    }
}

// ---------- per-edge scores + degree histogram ----------
__global__ __launch_bounds__(256) void edge_kernel(const int* __restrict__ ei,
                                                   const float* __restrict__ ea,
                                                   const float* __restrict__ s_src,
                                                   const float* __restrict__ s_dst,
                                                   const float* __restrict__ weff,
                                                   const int* __restrict__ flag,
                                                   float* __restrict__ att,
                                                   int* __restrict__ deg, int E, int n) {
    __shared__ float we[128];
    if (threadIdx.x < 128) we[threadIdx.x] = weff[threadIdx.x];
    __syncthreads();
    int e = blockIdx.x * blockDim.x + threadIdx.x;
    int EP = E + n;
    if (e >= EP) return;
    int is64 = *flag;
    int s, d;
    load_edge(ei, e, E, n, is64, s, d);
    float4 vs = *(const float4*)&s_src[(size_t)s * 4];
    float4 vd = *(const float4*)&s_dst[(size_t)d * 4];
    float ed[4] = {0.f, 0.f, 0.f, 0.f};
    if (e < E) {
#pragma unroll
        for (int k = 0; k < EDGE_DIM; k += 4) {
            float4 v = *(const float4*)&ea[(size_t)e * EDGE_DIM + k];
#pragma unroll
            for (int h = 0; h < 4; ++h) {
                ed[h] += v.x * we[h * 32 + k + 0] + v.y * we[h * 32 + k + 1] +
                         v.z * we[h * 32 + k + 2] + v.w * we[h * 32 + k + 3];
            }
        }
    }
    float t0 = vs.x + vd.x + ed[0];
    float t1 = vs.y + vd.y + ed[1];
    float t2 = vs.z + vd.z + ed[2];
    float t3 = vs.w + vd.w + ed[3];
    float4 o;
    o.x = t0 >= 0.f ? t0 : NEG_SLOPE * t0;
    o.y = t1 >= 0.f ? t1 : NEG_SLOPE * t1;
    o.z = t2 >= 0.f ? t2 : NEG_SLOPE * t2;
    o.w = t3 >= 0.f ? t3 : NEG_SLOPE * t3;
    *(float4*)&att[(size_t)e * 4] = o;
    atomicAdd(&deg[d], 1);
}

// ---------- single-block exclusive scan over deg ----------
#define SCAN_T 1024
__global__ __launch_bounds__(SCAN_T) void scan_kernel(const int* __restrict__ deg,
                                                      int* __restrict__ rowptr,
                                                      int* __restrict__ cursor, int n) {
    __shared__ int sdata[SCAN_T];
    int t = threadIdx.x;
    int per = (n + SCAN_T - 1) / SCAN_T;
    int begin = t * per;
    int endi = begin + per;
    if (endi > n) endi = n;
    int s = 0;
    for (int i = begin; i < endi; ++i) s += deg[i];
    sdata[t] = s;
    __syncthreads();
    for (int off = 1; off < SCAN_T; off <<= 1) {
        int v = 0;
        if (t >= off) v = sdata[t - off];
        __syncthreads();
        sdata[t] += v;
        __syncthreads();
    }
    int run = (t == 0) ? 0 : sdata[t - 1];
    for (int i = begin; i < endi; ++i) {
        int dv = deg[i];
        rowptr[i] = run;
        cursor[i] = run;
        run += dv;
    }
    if (t == SCAN_T - 1) rowptr[n] = run;
}

// ---------- scatter edges into CSR buckets; reorder att into CSR order ----------
__global__ __launch_bounds__(256) void scatter_kernel(const int* __restrict__ ei,
                                                      const float* __restrict__ att,
                                                      const int* __restrict__ flag,
                                                      int* __restrict__ cursor,
                                                      int* __restrict__ ssrc,
                                                      float* __restrict__ att_csr,
                                                      int E, int n) {
    int e = blockIdx.x * blockDim.x + threadIdx.x;
    int EP = E + n;
    if (e >= EP) return;
    int is64 = *flag;
    int s, d;
    load_edge(ei, e, E, n, is64, s, d);
    float4 a = *(const float4*)&att[(size_t)e * 4];
    int pos = atomicAdd(&cursor[d], 1);
    ssrc[pos] = s;
    *(float4*)&att_csr[(size_t)pos * 4] = a;
}

// ---------- softmax + aggregation: one wave per node, fp16 row gather ----------
__global__ __launch_bounds__(256) void agg_kernel(const int* __restrict__ rowptr,
                                                  const int* __restrict__ ssrc,
                                                  const float* __restrict__ att_csr,
                                                  const _Float16* __restrict__ xph,
                                                  const float* __restrict__ bias,
                                                  float* __restrict__ out, int n) {
    int wid = (blockIdx.x * blockDim.x + threadIdx.x) >> 6;
    int lane = threadIdx.x & 63;
    if (wid >= n) return;
    int start = rowptr[wid];
    int end = rowptr[wid + 1];

    float m0 = -1e30f, m1 = -1e30f, m2 = -1e30f, m3 = -1e30f;
    for (int i = start + lane; i < end; i += 64) {
        float4 a = *(const float4*)&att_csr[(size_t)i * 4];
        m0 = fmaxf(m0, a.x); m1 = fmaxf(m1, a.y);
        m2 = fmaxf(m2, a.z); m3 = fmaxf(m3, a.w);
    }
#pragma unroll
    for (int o = 1; o < 64; o <<= 1) {
        m0 = fmaxf(m0, __shfl_xor(m0, o));
        m1 = fmaxf(m1, __shfl_xor(m1, o));
        m2 = fmaxf(m2, __shfl_xor(m2, o));
        m3 = fmaxf(m3, __shfl_xor(m3, o));
    }
    float d0 = 0.f, d1 = 0.f, d2 = 0.f, d3 = 0.f;
    for (int i = start + lane; i < end; i += 64) {
        float4 a = *(const float4*)&att_csr[(size_t)i * 4];
        d0 += expf(a.x - m0); d1 += expf(a.y - m1);
        d2 += expf(a.z - m2); d3 += expf(a.w - m3);
    }
#pragma unroll
    for (int o = 1; o < 64; o <<= 1) {
        d0 += __shfl_xor(d0, o);
        d1 += __shfl_xor(d1, o);
        d2 += __shfl_xor(d2, o);
        d3 += __shfl_xor(d3, o);
    }
    int h = lane >> 4;
    float mh = h == 0 ? m0 : (h == 1 ? m1 : (h == 2 ? m2 : m3));
    float dh = h == 0 ? d0 : (h == 1 ? d1 : (h == 2 ? d2 : d3));
    float invh = 1.f / (dh + 1e-12f);

    float ax = 0.f, ay = 0.f, az = 0.f, aw = 0.f;
    int i = start;
    for (; i + 2 <= end; i += 2) {
        int s0 = ssrc[i];
        int s1 = ssrc[i + 1];
        float a0 = att_csr[(size_t)i * 4 + h];
        float a1 = att_csr[(size_t)(i + 1) * 4 + h];
        f16x4 x0 = *(const f16x4*)&xph[(size_t)s0 * HD + lane * 4];
        f16x4 x1 = *(const f16x4*)&xph[(size_t)s1 * HD + lane * 4];
        float al0 = expf(a0 - mh) * invh;
        float al1 = expf(a1 - mh) * invh;
        ax += al0 * (float)x0[0] + al1 * (float)x1[0];
        ay += al0 * (float)x0[1] + al1 * (float)x1[1];
        az += al0 * (float)x0[2] + al1 * (float)x1[2];
        aw += al0 * (float)x0[3] + al1 * (float)x1[3];
    }
    if (i < end) {
        int s0 = ssrc[i];
        float a0 = att_csr[(size_t)i * 4 + h];
        f16x4 x0 = *(const f16x4*)&xph[(size_t)s0 * HD + lane * 4];
        float al0 = expf(a0 - mh) * invh;
        ax += al0 * (float)x0[0];
        ay += al0 * (float)x0[1];
        az += al0 * (float)x0[2];
        aw += al0 * (float)x0[3];
    }
    float4 b = *(const float4*)&bias[lane * 4];
    float4 o4;
    o4.x = ax + b.x; o4.y = ay + b.y; o4.z = az + b.z; o4.w = aw + b.w;
    *(float4*)&out[(size_t)wid * HD + lane * 4] = o4;
}

extern "C" void kernel_launch(void* const* d_in, const int* in_sizes, int n_in,
                              void* d_out, int out_size, void* d_ws, size_t ws_size,
                              hipStream_t stream) {
    const float* x        = (const float*)d_in[0];
    const int*   ei       = (const int*)d_in[1];
    const float* ea       = (const float*)d_in[2];
    const float* lin_W    = (const float*)d_in[3];
    const float* att_src  = (const float*)d_in[4];
    const float* att_dst  = (const float*)d_in[5];
    const float* lin_eW   = (const float*)d_in[6];
    const float* att_edge = (const float*)d_in[7];
    const float* bias     = (const float*)d_in[8];
    float* out = (float*)d_out;

    int n  = in_sizes[0] / IN_DIM;     // 20000
    int E  = in_sizes[2] / EDGE_DIM;   // 320000
    int EP = E + n;

    char* p = (char*)d_ws;
    auto alloc = [&](size_t bytes) {
        char* r = p;
        p += (bytes + 255) & ~(size_t)255;
        return r;
    };
    _Float16* xph   = (_Float16*)alloc((size_t)n * HD * 2);
    float* s_src    = (float*)alloc((size_t)n * 4 * 4);
    float* s_dst    = (float*)alloc((size_t)n * 4 * 4);
    float* att      = (float*)alloc((size_t)EP * 4 * 4);
    float* att_csr  = (float*)alloc((size_t)EP * 4 * 4);
    float* weff     = (float*)alloc(128 * 4);
    int*   deg      = (int*)alloc((size_t)n * 4);
    int*   rowptr   = (int*)alloc((size_t)(n + 1) * 4);
    int*   cursor   = (int*)alloc((size_t)n * 4);
    int*   ssrc     = (int*)alloc((size_t)EP * 4);
    int*   flag     = (int*)alloc(4);

    prep_kernel<<<2 + (n + 255) / 256, 256, 0, stream>>>(ei, lin_eW, att_edge, weff, deg,
                                                         flag, n);
    proj_kernel<<<(n + 63) / 64, 256, 0, stream>>>(x, lin_W, xph, n);
    sscore_kernel<<<(n + 3) / 4, 256, 0, stream>>>(xph, att_src, att_dst, s_src, s_dst, n);
    edge_kernel<<<(EP + 255) / 256, 256, 0, stream>>>(ei, ea, s_src, s_dst, weff, flag,
                                                      att, deg, E, n);
    scan_kernel<<<1, SCAN_T, 0, stream>>>(deg, rowptr, cursor, n);
    scatter_kernel<<<(EP + 255) / 256, 256, 0, stream>>>(ei, att, flag, cursor, ssrc,
                                                         att_csr, E, n);
    agg_kernel<<<(n + 3) / 4, 256, 0, stream>>>(rowptr, ssrc, att_csr, xph, bias, out, n);
}

// Round 3
// 157.976 us; speedup vs baseline: 1.4049x; 1.0332x over previous
//
#include <hip/hip_runtime.h>
#include <math.h>

#define IN_DIM 256
#define HD 256
#define EDGE_DIM 32
#define NEG_SLOPE 0.2f
#define CAP 128
#define PSTRIDE 136

typedef _Float16 f16x8 __attribute__((ext_vector_type(8)));
typedef _Float16 f16x4 __attribute__((ext_vector_type(4)));
typedef float f32x4 __attribute__((ext_vector_type(4)));

__device__ __forceinline__ void load_edge(const int* ei, int e, int E, int n, int is64,
                                          int& s, int& d) {
    if (e < E) {
        if (is64) { s = ei[2 * e]; d = ei[2 * E + 2 * e]; }
        else      { s = ei[e];     d = ei[E + e]; }
    } else {
        s = d = e - E;  // self loop
    }
}

__device__ __forceinline__ f16x8 cvt8(const float* p) {
    float4 lo = *(const float4*)p;
    float4 hi = *(const float4*)(p + 4);
    auto a = __builtin_amdgcn_cvt_pkrtz(lo.x, lo.y);
    auto b = __builtin_amdgcn_cvt_pkrtz(lo.z, lo.w);
    auto c = __builtin_amdgcn_cvt_pkrtz(hi.x, hi.y);
    auto d = __builtin_amdgcn_cvt_pkrtz(hi.z, hi.w);
    f16x8 r;
    r[0] = (_Float16)a[0]; r[1] = (_Float16)a[1];
    r[2] = (_Float16)b[0]; r[3] = (_Float16)b[1];
    r[4] = (_Float16)c[0]; r[5] = (_Float16)c[1];
    r[6] = (_Float16)d[0]; r[7] = (_Float16)d[1];
    return r;
}

// ---------- prep: weff (b0), int64-detect (b1), deg=1 (b2..) ----------
__global__ __launch_bounds__(256) void prep_kernel(const int* __restrict__ ei,
                                                   const float* __restrict__ lew,
                                                   const float* __restrict__ ae,
                                                   float* __restrict__ weff,
                                                   int* __restrict__ deg,
                                                   int* __restrict__ flag, int n) {
    int b = blockIdx.x;
    if (b == 0) {
        int t = threadIdx.x;
        if (t < 128) {
            int h = t >> 5, k = t & 31;
            float s = 0.f;
#pragma unroll 8
            for (int d = 0; d < 64; ++d) s += lew[(h * 64 + d) * 32 + k] * ae[h * 64 + d];
            weff[t] = s;
        }
    } else if (b == 1) {
        __shared__ int anynz;
        if (threadIdx.x == 0) anynz = 0;
        __syncthreads();
        int v = ei[2 * threadIdx.x + 1];  // high words if int64 (node ids >= 0)
        if (v != 0) atomicOr(&anynz, 1);
        __syncthreads();
        if (threadIdx.x == 0) *flag = (anynz == 0) ? 1 : 0;
    } else {
        int i = (b - 2) * 256 + threadIdx.x;
        if (i < n) deg[i] = 1;  // self-loop pre-counted
    }
}

// ---------- degree histogram over real edges only ----------
__global__ __launch_bounds__(256) void deg_kernel(const int* __restrict__ ei,
                                                  const int* __restrict__ flag,
                                                  int* __restrict__ deg, int E) {
    int e = blockIdx.x * blockDim.x + threadIdx.x;
    if (e >= E) return;
    int is64 = *flag;
    int d = is64 ? ei[2 * E + 2 * e] : ei[E + e];
    atomicAdd(&deg[d], 1);
}

// ---------- x_proj (fp16) via MFMA + fused s_src/s_dst epilogue ----------
__global__ __launch_bounds__(256) void proj_kernel(const float* __restrict__ x,
                                                   const float* __restrict__ W,
                                                   const float* __restrict__ asrc_g,
                                                   const float* __restrict__ adst_g,
                                                   _Float16* __restrict__ xph,
                                                   float* __restrict__ s_src,
                                                   float* __restrict__ s_dst, int n) {
    int tid = threadIdx.x;
    int lane = tid & 63;
    int w = tid >> 6;            // wave id == head id (col group)
    int m0 = blockIdx.x * 64;
    int c0 = w * 64;
    int r = lane & 15;
    int kq = lane >> 4;          // 0..3

    float asr[4], ads[4];
#pragma unroll
    for (int ci = 0; ci < 4; ++ci) {
        asr[ci] = asrc_g[c0 + ci * 16 + r];
        ads[ci] = adst_g[c0 + ci * 16 + r];
    }

    f32x4 acc[4][4];
#pragma unroll
    for (int i = 0; i < 4; ++i)
#pragma unroll
        for (int j = 0; j < 4; ++j) acc[i][j] = (f32x4){0.f, 0.f, 0.f, 0.f};

    for (int k0 = 0; k0 < IN_DIM; k0 += 32) {
        int kk = k0 + kq * 8;
        f16x8 a[4], bfr[4];
#pragma unroll
        for (int mi = 0; mi < 4; ++mi) {
            int row = m0 + mi * 16 + r;
            f16x8 av = {0, 0, 0, 0, 0, 0, 0, 0};
            if (row < n) av = cvt8(&x[(size_t)row * IN_DIM + kk]);
            a[mi] = av;
        }
#pragma unroll
        for (int ci = 0; ci < 4; ++ci)
            bfr[ci] = cvt8(&W[(size_t)(c0 + ci * 16 + r) * IN_DIM + kk]);
#pragma unroll
        for (int mi = 0; mi < 4; ++mi)
#pragma unroll
            for (int ci = 0; ci < 4; ++ci)
                acc[mi][ci] = __builtin_amdgcn_mfma_f32_16x16x32_f16(a[mi], bfr[ci],
                                                                     acc[mi][ci], 0, 0, 0);
    }
    // C/D layout: col = lane&15, row = (lane>>4)*4 + j
#pragma unroll
    for (int mi = 0; mi < 4; ++mi) {
#pragma unroll
        for (int j = 0; j < 4; ++j) {
            int row = m0 + mi * 16 + kq * 4 + j;
            if (row < n) {
#pragma unroll
                for (int ci = 0; ci < 4; ++ci)
                    xph[(size_t)row * HD + c0 + ci * 16 + r] = (_Float16)acc[mi][ci][j];
            }
        }
    }
    // fused attention scores: wave w == head w owns cols [w*64, w*64+64)
#pragma unroll
    for (int mi = 0; mi < 4; ++mi) {
#pragma unroll
        for (int j = 0; j < 4; ++j) {
            float vs = 0.f, vd = 0.f;
#pragma unroll
            for (int ci = 0; ci < 4; ++ci) {
                vs += acc[mi][ci][j] * asr[ci];
                vd += acc[mi][ci][j] * ads[ci];
            }
#pragma unroll
            for (int msk = 1; msk < 16; msk <<= 1) {
                vs += __shfl_xor(vs, msk);
                vd += __shfl_xor(vd, msk);
            }
            int row = m0 + mi * 16 + kq * 4 + j;
            if (r == 0 && row < n) {
                s_src[row * 4 + w] = vs;
                s_dst[row * 4 + w] = vd;
            }
        }
    }
}

// ---------- single-block exclusive scan over deg ----------
#define SCAN_T 1024
__global__ __launch_bounds__(SCAN_T) void scan_kernel(const int* __restrict__ deg,
                                                      int* __restrict__ rowptr,
                                                      int* __restrict__ cursor, int n) {
    __shared__ int sdata[SCAN_T];
    int t = threadIdx.x;
    int per = (n + SCAN_T - 1) / SCAN_T;
    int begin = t * per;
    int endi = begin + per;
    if (endi > n) endi = n;
    int s = 0;
    for (int i = begin; i < endi; ++i) s += deg[i];
    sdata[t] = s;
    __syncthreads();
    for (int off = 1; off < SCAN_T; off <<= 1) {
        int v = 0;
        if (t >= off) v = sdata[t - off];
        __syncthreads();
        sdata[t] += v;
        __syncthreads();
    }
    int run = (t == 0) ? 0 : sdata[t - 1];
    for (int i = begin; i < endi; ++i) {
        int dv = deg[i];
        rowptr[i] = run;
        cursor[i] = run;
        run += dv;
    }
    if (t == SCAN_T - 1) rowptr[n] = run;
}

// ---------- fused edge scoring + CSR scatter ----------
__global__ __launch_bounds__(256) void scatter_kernel(const int* __restrict__ ei,
                                                      const float* __restrict__ ea,
                                                      const float* __restrict__ s_src,
                                                      const float* __restrict__ s_dst,
                                                      const float* __restrict__ weff,
                                                      const int* __restrict__ flag,
                                                      int* __restrict__ cursor,
                                                      int* __restrict__ ssrc,
                                                      float* __restrict__ att_csr,
                                                      int E, int n) {
    __shared__ float we[128];
    if (threadIdx.x < 128) we[threadIdx.x] = weff[threadIdx.x];
    __syncthreads();
    int e = blockIdx.x * blockDim.x + threadIdx.x;
    int EP = E + n;
    if (e >= EP) return;
    int is64 = *flag;
    int s, d;
    load_edge(ei, e, E, n, is64, s, d);
    float4 vs = *(const float4*)&s_src[(size_t)s * 4];
    float4 vd = *(const float4*)&s_dst[(size_t)d * 4];
    float ed[4] = {0.f, 0.f, 0.f, 0.f};
    if (e < E) {
#pragma unroll
        for (int k = 0; k < EDGE_DIM; k += 4) {
            float4 v = *(const float4*)&ea[(size_t)e * EDGE_DIM + k];
#pragma unroll
            for (int h = 0; h < 4; ++h) {
                ed[h] += v.x * we[h * 32 + k + 0] + v.y * we[h * 32 + k + 1] +
                         v.z * we[h * 32 + k + 2] + v.w * we[h * 32 + k + 3];
            }
        }
    }
    float t0 = vs.x + vd.x + ed[0];
    float t1 = vs.y + vd.y + ed[1];
    float t2 = vs.z + vd.z + ed[2];
    float t3 = vs.w + vd.w + ed[3];
    float4 o;
    o.x = t0 >= 0.f ? t0 : NEG_SLOPE * t0;
    o.y = t1 >= 0.f ? t1 : NEG_SLOPE * t1;
    o.z = t2 >= 0.f ? t2 : NEG_SLOPE * t2;
    o.w = t3 >= 0.f ? t3 : NEG_SLOPE * t3;
    int pos = atomicAdd(&cursor[d], 1);
    ssrc[pos] = s;
    *(float4*)&att_csr[(size_t)pos * 4] = o;
}

// ---------- softmax + aggregation: one wave per node, LDS-cached alphas ----------
__global__ __launch_bounds__(256) void agg_kernel(const int* __restrict__ rowptr,
                                                  const int* __restrict__ ssrc,
                                                  const float* __restrict__ att_csr,
                                                  const _Float16* __restrict__ xph,
                                                  const float* __restrict__ bias,
                                                  float* __restrict__ out, int n) {
    __shared__ float pl[4][4 * PSTRIDE];
    int wv = threadIdx.x >> 6;
    float* pbuf = pl[wv];
    int wid = (blockIdx.x * blockDim.x + threadIdx.x) >> 6;
    int lane = threadIdx.x & 63;
    if (wid >= n) return;
    int start = rowptr[wid];
    int end = rowptr[wid + 1];
    int deg = end - start;

    float m0 = -1e30f, m1 = -1e30f, m2 = -1e30f, m3 = -1e30f;
    for (int i = start + lane; i < end; i += 64) {
        float4 a = *(const float4*)&att_csr[(size_t)i * 4];
        m0 = fmaxf(m0, a.x); m1 = fmaxf(m1, a.y);
        m2 = fmaxf(m2, a.z); m3 = fmaxf(m3, a.w);
    }
#pragma unroll
    for (int o = 1; o < 64; o <<= 1) {
        m0 = fmaxf(m0, __shfl_xor(m0, o));
        m1 = fmaxf(m1, __shfl_xor(m1, o));
        m2 = fmaxf(m2, __shfl_xor(m2, o));
        m3 = fmaxf(m3, __shfl_xor(m3, o));
    }
    float d0 = 0.f, d1 = 0.f, d2 = 0.f, d3 = 0.f;
    for (int i = start + lane; i < end; i += 64) {
        float4 a = *(const float4*)&att_csr[(size_t)i * 4];
        float p0 = __expf(a.x - m0);
        float p1 = __expf(a.y - m1);
        float p2 = __expf(a.z - m2);
        float p3 = __expf(a.w - m3);
        int idx = i - start;
        if (idx < CAP) {
            pbuf[0 * PSTRIDE + idx] = p0;
            pbuf[1 * PSTRIDE + idx] = p1;
            pbuf[2 * PSTRIDE + idx] = p2;
            pbuf[3 * PSTRIDE + idx] = p3;
        }
        d0 += p0; d1 += p1; d2 += p2; d3 += p3;
    }
#pragma unroll
    for (int o = 1; o < 64; o <<= 1) {
        d0 += __shfl_xor(d0, o);
        d1 += __shfl_xor(d1, o);
        d2 += __shfl_xor(d2, o);
        d3 += __shfl_xor(d3, o);
    }
    int h = lane >> 4;
    float mh = h == 0 ? m0 : (h == 1 ? m1 : (h == 2 ? m2 : m3));
    float dh = h == 0 ? d0 : (h == 1 ? d1 : (h == 2 ? d2 : d3));
    float invh = 1.f / (dh + 1e-12f);
    const float* ph = &pbuf[h * PSTRIDE];

    float ax = 0.f, ay = 0.f, az = 0.f, aw = 0.f;
    int idx = 0;
    for (; idx + 2 <= deg; idx += 2) {
        int s0 = ssrc[start + idx];
        int s1 = ssrc[start + idx + 1];
        float p0 = (idx < CAP) ? ph[idx]
                               : __expf(att_csr[(size_t)(start + idx) * 4 + h] - mh);
        float p1 = (idx + 1 < CAP) ? ph[idx + 1]
                               : __expf(att_csr[(size_t)(start + idx + 1) * 4 + h] - mh);
        f16x4 x0 = *(const f16x4*)&xph[(size_t)s0 * HD + lane * 4];
        f16x4 x1 = *(const f16x4*)&xph[(size_t)s1 * HD + lane * 4];
        float al0 = p0 * invh;
        float al1 = p1 * invh;
        ax += al0 * (float)x0[0] + al1 * (float)x1[0];
        ay += al0 * (float)x0[1] + al1 * (float)x1[1];
        az += al0 * (float)x0[2] + al1 * (float)x1[2];
        aw += al0 * (float)x0[3] + al1 * (float)x1[3];
    }
    if (idx < deg) {
        int s0 = ssrc[start + idx];
        float p0 = (idx < CAP) ? ph[idx]
                               : __expf(att_csr[(size_t)(start + idx) * 4 + h] - mh);
        f16x4 x0 = *(const f16x4*)&xph[(size_t)s0 * HD + lane * 4];
        float al0 = p0 * invh;
        ax += al0 * (float)x0[0];
        ay += al0 * (float)x0[1];
        az += al0 * (float)x0[2];
        aw += al0 * (float)x0[3];
    }
    float4 b = *(const float4*)&bias[lane * 4];
    float4 o4;
    o4.x = ax + b.x; o4.y = ay + b.y; o4.z = az + b.z; o4.w = aw + b.w;
    *(float4*)&out[(size_t)wid * HD + lane * 4] = o4;
}

extern "C" void kernel_launch(void* const* d_in, const int* in_sizes, int n_in,
                              void* d_out, int out_size, void* d_ws, size_t ws_size,
                              hipStream_t stream) {
    const float* x        = (const float*)d_in[0];
    const int*   ei       = (const int*)d_in[1];
    const float* ea       = (const float*)d_in[2];
    const float* lin_W    = (const float*)d_in[3];
    const float* att_src  = (const float*)d_in[4];
    const float* att_dst  = (const float*)d_in[5];
    const float* lin_eW   = (const float*)d_in[6];
    const float* att_edge = (const float*)d_in[7];
    const float* bias     = (const float*)d_in[8];
    float* out = (float*)d_out;

    int n  = in_sizes[0] / IN_DIM;     // 20000
    int E  = in_sizes[2] / EDGE_DIM;   // 320000
    int EP = E + n;

    char* p = (char*)d_ws;
    auto alloc = [&](size_t bytes) {
        char* r = p;
        p += (bytes + 255) & ~(size_t)255;
        return r;
    };
    _Float16* xph   = (_Float16*)alloc((size_t)n * HD * 2);
    float* s_src    = (float*)alloc((size_t)n * 4 * 4);
    float* s_dst    = (float*)alloc((size_t)n * 4 * 4);
    float* att_csr  = (float*)alloc((size_t)EP * 4 * 4);
    float* weff     = (float*)alloc(128 * 4);
    int*   deg      = (int*)alloc((size_t)n * 4);
    int*   rowptr   = (int*)alloc((size_t)(n + 1) * 4);
    int*   cursor   = (int*)alloc((size_t)n * 4);
    int*   ssrc     = (int*)alloc((size_t)EP * 4);
    int*   flag     = (int*)alloc(4);

    prep_kernel<<<2 + (n + 255) / 256, 256, 0, stream>>>(ei, lin_eW, att_edge, weff, deg,
                                                         flag, n);
    deg_kernel<<<(E + 255) / 256, 256, 0, stream>>>(ei, flag, deg, E);
    proj_kernel<<<(n + 63) / 64, 256, 0, stream>>>(x, lin_W, att_src, att_dst, xph,
                                                   s_src, s_dst, n);
    scan_kernel<<<1, SCAN_T, 0, stream>>>(deg, rowptr, cursor, n);
    scatter_kernel<<<(EP + 255) / 256, 256, 0, stream>>>(ei, ea, s_src, s_dst, weff, flag,
                                                         cursor, ssrc, att_csr, E, n);
    agg_kernel<<<(n + 3) / 4, 256, 0, stream>>>(rowptr, ssrc, att_csr, xph, bias, out, n);
}

// Round 4
// 152.175 us; speedup vs baseline: 1.4584x; 1.0381x over previous
//
#include <hip/hip_runtime.h>
#include <math.h>

#define IN_DIM 256
#define HD 256
#define EDGE_DIM 32
#define NEG_SLOPE 0.2f
#define CAP 128
#define PSTRIDE 136

typedef _Float16 f16x8 __attribute__((ext_vector_type(8)));
typedef _Float16 f16x4 __attribute__((ext_vector_type(4)));
typedef float f32x4 __attribute__((ext_vector_type(4)));

__device__ __forceinline__ void load_edge(const int* ei, int e, int E, int n, int is64,
                                          int& s, int& d) {
    if (e < E) {
        if (is64) { s = ei[2 * e]; d = ei[2 * E + 2 * e]; }
        else      { s = ei[e];     d = ei[E + e]; }
    } else {
        s = d = e - E;  // self loop
    }
}

__device__ __forceinline__ f16x8 cvt8(const float* p) {
    float4 lo = *(const float4*)p;
    float4 hi = *(const float4*)(p + 4);
    auto a = __builtin_amdgcn_cvt_pkrtz(lo.x, lo.y);
    auto b = __builtin_amdgcn_cvt_pkrtz(lo.z, lo.w);
    auto c = __builtin_amdgcn_cvt_pkrtz(hi.x, hi.y);
    auto d = __builtin_amdgcn_cvt_pkrtz(hi.z, hi.w);
    f16x8 r;
    r[0] = (_Float16)a[0]; r[1] = (_Float16)a[1];
    r[2] = (_Float16)b[0]; r[3] = (_Float16)b[1];
    r[4] = (_Float16)c[0]; r[5] = (_Float16)c[1];
    r[6] = (_Float16)d[0]; r[7] = (_Float16)d[1];
    return r;
}

// ---------- prep: weff (b0), int64-detect (b1), W->fp16 (b2..33), deg=1 (b34..) ----------
#define WCVT_BLOCKS 32
__global__ __launch_bounds__(256) void prep_kernel(const int* __restrict__ ei,
                                                   const float* __restrict__ lew,
                                                   const float* __restrict__ ae,
                                                   const float* __restrict__ W,
                                                   float* __restrict__ weff,
                                                   _Float16* __restrict__ Wh,
                                                   int* __restrict__ deg,
                                                   int* __restrict__ flag, int n) {
    int b = blockIdx.x;
    if (b == 0) {
        int t = threadIdx.x;
        if (t < 128) {
            int h = t >> 5, k = t & 31;
            float s = 0.f;
#pragma unroll 8
            for (int d = 0; d < 64; ++d) s += lew[(h * 64 + d) * 32 + k] * ae[h * 64 + d];
            weff[t] = s;
        }
    } else if (b == 1) {
        __shared__ int anynz;
        if (threadIdx.x == 0) anynz = 0;
        __syncthreads();
        int v = ei[2 * threadIdx.x + 1];  // high words if int64 (node ids >= 0)
        if (v != 0) atomicOr(&anynz, 1);
        __syncthreads();
        if (threadIdx.x == 0) *flag = (anynz == 0) ? 1 : 0;
    } else if (b < 2 + WCVT_BLOCKS) {
        int idx = (b - 2) * 2048 + threadIdx.x * 8;
        *(f16x8*)&Wh[idx] = cvt8(&W[idx]);
    } else {
        int i = (b - 2 - WCVT_BLOCKS) * 256 + threadIdx.x;
        if (i < n) deg[i] = 1;  // self-loop pre-counted
    }
}

// ---------- degree histogram over real edges only ----------
__global__ __launch_bounds__(256) void deg_kernel(const int* __restrict__ ei,
                                                  const int* __restrict__ flag,
                                                  int* __restrict__ deg, int E) {
    int e = blockIdx.x * blockDim.x + threadIdx.x;
    if (e >= E) return;
    int is64 = *flag;
    int d = is64 ? ei[2 * E + 2 * e] : ei[E + e];
    atomicAdd(&deg[d], 1);
}

// ---------- x_proj (fp16) via MFMA, 16 rows/block, fused s_src/s_dst epilogue ----------
__global__ __launch_bounds__(256) void proj_kernel(const float* __restrict__ x,
                                                   const _Float16* __restrict__ Wh,
                                                   const float* __restrict__ asrc_g,
                                                   const float* __restrict__ adst_g,
                                                   _Float16* __restrict__ xph,
                                                   float* __restrict__ s_src,
                                                   float* __restrict__ s_dst, int n) {
    int tid = threadIdx.x;
    int lane = tid & 63;
    int w = tid >> 6;            // wave id == head id (col group)
    int m0 = blockIdx.x * 16;
    int c0 = w * 64;
    int r = lane & 15;
    int kq = lane >> 4;          // 0..3

    float asr[4], ads[4];
#pragma unroll
    for (int ci = 0; ci < 4; ++ci) {
        asr[ci] = asrc_g[c0 + ci * 16 + r];
        ads[ci] = adst_g[c0 + ci * 16 + r];
    }

    f32x4 acc[4];
#pragma unroll
    for (int j = 0; j < 4; ++j) acc[j] = (f32x4){0.f, 0.f, 0.f, 0.f};

    int row = m0 + r;
    bool rok = row < n;
#pragma unroll
    for (int k0 = 0; k0 < IN_DIM; k0 += 32) {
        int kk = k0 + kq * 8;
        f16x8 a = {0, 0, 0, 0, 0, 0, 0, 0};
        if (rok) a = cvt8(&x[(size_t)row * IN_DIM + kk]);
        f16x8 bfr[4];
#pragma unroll
        for (int ci = 0; ci < 4; ++ci)
            bfr[ci] = *(const f16x8*)&Wh[(size_t)(c0 + ci * 16 + r) * IN_DIM + kk];
#pragma unroll
        for (int ci = 0; ci < 4; ++ci)
            acc[ci] = __builtin_amdgcn_mfma_f32_16x16x32_f16(a, bfr[ci], acc[ci], 0, 0, 0);
    }
    // C/D layout: col = lane&15, row = (lane>>4)*4 + j
#pragma unroll
    for (int j = 0; j < 4; ++j) {
        int orow = m0 + kq * 4 + j;
        if (orow < n) {
#pragma unroll
            for (int ci = 0; ci < 4; ++ci)
                xph[(size_t)orow * HD + c0 + ci * 16 + r] = (_Float16)acc[ci][j];
        }
    }
    // fused attention scores: wave w == head w owns cols [w*64, w*64+64)
#pragma unroll
    for (int j = 0; j < 4; ++j) {
        float vs = 0.f, vd = 0.f;
#pragma unroll
        for (int ci = 0; ci < 4; ++ci) {
            vs += acc[ci][j] * asr[ci];
            vd += acc[ci][j] * ads[ci];
        }
#pragma unroll
        for (int msk = 1; msk < 16; msk <<= 1) {
            vs += __shfl_xor(vs, msk);
            vd += __shfl_xor(vd, msk);
        }
        int orow = m0 + kq * 4 + j;
        if (r == 0 && orow < n) {
            s_src[orow * 4 + w] = vs;
            s_dst[orow * 4 + w] = vd;
        }
    }
}

// ---------- single-block exclusive scan over deg ----------
#define SCAN_T 1024
__global__ __launch_bounds__(SCAN_T) void scan_kernel(const int* __restrict__ deg,
                                                      int* __restrict__ rowptr,
                                                      int* __restrict__ cursor, int n) {
    __shared__ int sdata[SCAN_T];
    int t = threadIdx.x;
    int per = (n + SCAN_T - 1) / SCAN_T;
    int begin = t * per;
    int endi = begin + per;
    if (endi > n) endi = n;
    int s = 0;
    for (int i = begin; i < endi; ++i) s += deg[i];
    sdata[t] = s;
    __syncthreads();
    for (int off = 1; off < SCAN_T; off <<= 1) {
        int v = 0;
        if (t >= off) v = sdata[t - off];
        __syncthreads();
        sdata[t] += v;
        __syncthreads();
    }
    int run = (t == 0) ? 0 : sdata[t - 1];
    for (int i = begin; i < endi; ++i) {
        int dv = deg[i];
        rowptr[i] = run;
        cursor[i] = run;
        run += dv;
    }
    if (t == SCAN_T - 1) rowptr[n] = run;
}

// ---------- fused edge scoring + CSR scatter ----------
__global__ __launch_bounds__(256) void scatter_kernel(const int* __restrict__ ei,
                                                      const float* __restrict__ ea,
                                                      const float* __restrict__ s_src,
                                                      const float* __restrict__ s_dst,
                                                      const float* __restrict__ weff,
                                                      const int* __restrict__ flag,
                                                      int* __restrict__ cursor,
                                                      int* __restrict__ ssrc,
                                                      float* __restrict__ att_csr,
                                                      int E, int n) {
    __shared__ float we[128];
    if (threadIdx.x < 128) we[threadIdx.x] = weff[threadIdx.x];
    __syncthreads();
    int e = blockIdx.x * blockDim.x + threadIdx.x;
    int EP = E + n;
    if (e >= EP) return;
    int is64 = *flag;
    int s, d;
    load_edge(ei, e, E, n, is64, s, d);
    float4 vs = *(const float4*)&s_src[(size_t)s * 4];
    float4 vd = *(const float4*)&s_dst[(size_t)d * 4];
    float ed[4] = {0.f, 0.f, 0.f, 0.f};
    if (e < E) {
#pragma unroll
        for (int k = 0; k < EDGE_DIM; k += 4) {
            float4 v = *(const float4*)&ea[(size_t)e * EDGE_DIM + k];
#pragma unroll
            for (int h = 0; h < 4; ++h) {
                ed[h] += v.x * we[h * 32 + k + 0] + v.y * we[h * 32 + k + 1] +
                         v.z * we[h * 32 + k + 2] + v.w * we[h * 32 + k + 3];
            }
        }
    }
    float t0 = vs.x + vd.x + ed[0];
    float t1 = vs.y + vd.y + ed[1];
    float t2 = vs.z + vd.z + ed[2];
    float t3 = vs.w + vd.w + ed[3];
    float4 o;
    o.x = t0 >= 0.f ? t0 : NEG_SLOPE * t0;
    o.y = t1 >= 0.f ? t1 : NEG_SLOPE * t1;
    o.z = t2 >= 0.f ? t2 : NEG_SLOPE * t2;
    o.w = t3 >= 0.f ? t3 : NEG_SLOPE * t3;
    int pos = atomicAdd(&cursor[d], 1);
    ssrc[pos] = s;
    *(float4*)&att_csr[(size_t)pos * 4] = o;
}

// ---------- softmax + aggregation: one wave per node, LDS-cached alphas ----------
__global__ __launch_bounds__(256) void agg_kernel(const int* __restrict__ rowptr,
                                                  const int* __restrict__ ssrc,
                                                  const float* __restrict__ att_csr,
                                                  const _Float16* __restrict__ xph,
                                                  const float* __restrict__ bias,
                                                  float* __restrict__ out, int n) {
    __shared__ float pl[4][4 * PSTRIDE];
    int wv = threadIdx.x >> 6;
    float* pbuf = pl[wv];
    int wid = (blockIdx.x * blockDim.x + threadIdx.x) >> 6;
    int lane = threadIdx.x & 63;
    if (wid >= n) return;
    int start = rowptr[wid];
    int end = rowptr[wid + 1];
    int deg = end - start;

    float m0 = -1e30f, m1 = -1e30f, m2 = -1e30f, m3 = -1e30f;
    for (int i = start + lane; i < end; i += 64) {
        float4 a = *(const float4*)&att_csr[(size_t)i * 4];
        m0 = fmaxf(m0, a.x); m1 = fmaxf(m1, a.y);
        m2 = fmaxf(m2, a.z); m3 = fmaxf(m3, a.w);
    }
#pragma unroll
    for (int o = 1; o < 64; o <<= 1) {
        m0 = fmaxf(m0, __shfl_xor(m0, o));
        m1 = fmaxf(m1, __shfl_xor(m1, o));
        m2 = fmaxf(m2, __shfl_xor(m2, o));
        m3 = fmaxf(m3, __shfl_xor(m3, o));
    }
    float d0 = 0.f, d1 = 0.f, d2 = 0.f, d3 = 0.f;
    for (int i = start + lane; i < end; i += 64) {
        float4 a = *(const float4*)&att_csr[(size_t)i * 4];
        float p0 = __expf(a.x - m0);
        float p1 = __expf(a.y - m1);
        float p2 = __expf(a.z - m2);
        float p3 = __expf(a.w - m3);
        int idx = i - start;
        if (idx < CAP) {
            pbuf[0 * PSTRIDE + idx] = p0;
            pbuf[1 * PSTRIDE + idx] = p1;
            pbuf[2 * PSTRIDE + idx] = p2;
            pbuf[3 * PSTRIDE + idx] = p3;
        }
        d0 += p0; d1 += p1; d2 += p2; d3 += p3;
    }
#pragma unroll
    for (int o = 1; o < 64; o <<= 1) {
        d0 += __shfl_xor(d0, o);
        d1 += __shfl_xor(d1, o);
        d2 += __shfl_xor(d2, o);
        d3 += __shfl_xor(d3, o);
    }
    int h = lane >> 4;
    float mh = h == 0 ? m0 : (h == 1 ? m1 : (h == 2 ? m2 : m3));
    float dh = h == 0 ? d0 : (h == 1 ? d1 : (h == 2 ? d2 : d3));
    float invh = 1.f / (dh + 1e-12f);
    const float* ph = &pbuf[h * PSTRIDE];

    float ax = 0.f, ay = 0.f, az = 0.f, aw = 0.f;
    int idx = 0;
    for (; idx + 2 <= deg; idx += 2) {
        int s0 = ssrc[start + idx];
        int s1 = ssrc[start + idx + 1];
        float p0 = (idx < CAP) ? ph[idx]
                               : __expf(att_csr[(size_t)(start + idx) * 4 + h] - mh);
        float p1 = (idx + 1 < CAP) ? ph[idx + 1]
                               : __expf(att_csr[(size_t)(start + idx + 1) * 4 + h] - mh);
        f16x4 x0 = *(const f16x4*)&xph[(size_t)s0 * HD + lane * 4];
        f16x4 x1 = *(const f16x4*)&xph[(size_t)s1 * HD + lane * 4];
        float al0 = p0 * invh;
        float al1 = p1 * invh;
        ax += al0 * (float)x0[0] + al1 * (float)x1[0];
        ay += al0 * (float)x0[1] + al1 * (float)x1[1];
        az += al0 * (float)x0[2] + al1 * (float)x1[2];
        aw += al0 * (float)x0[3] + al1 * (float)x1[3];
    }
    if (idx < deg) {
        int s0 = ssrc[start + idx];
        float p0 = (idx < CAP) ? ph[idx]
                               : __expf(att_csr[(size_t)(start + idx) * 4 + h] - mh);
        f16x4 x0 = *(const f16x4*)&xph[(size_t)s0 * HD + lane * 4];
        float al0 = p0 * invh;
        ax += al0 * (float)x0[0];
        ay += al0 * (float)x0[1];
        az += al0 * (float)x0[2];
        aw += al0 * (float)x0[3];
    }
    float4 b = *(const float4*)&bias[lane * 4];
    float4 o4;
    o4.x = ax + b.x; o4.y = ay + b.y; o4.z = az + b.z; o4.w = aw + b.w;
    *(float4*)&out[(size_t)wid * HD + lane * 4] = o4;
}

extern "C" void kernel_launch(void* const* d_in, const int* in_sizes, int n_in,
                              void* d_out, int out_size, void* d_ws, size_t ws_size,
                              hipStream_t stream) {
    const float* x        = (const float*)d_in[0];
    const int*   ei       = (const int*)d_in[1];
    const float* ea       = (const float*)d_in[2];
    const float* lin_W    = (const float*)d_in[3];
    const float* att_src  = (const float*)d_in[4];
    const float* att_dst  = (const float*)d_in[5];
    const float* lin_eW   = (const float*)d_in[6];
    const float* att_edge = (const float*)d_in[7];
    const float* bias     = (const float*)d_in[8];
    float* out = (float*)d_out;

    int n  = in_sizes[0] / IN_DIM;     // 20000
    int E  = in_sizes[2] / EDGE_DIM;   // 320000
    int EP = E + n;

    char* p = (char*)d_ws;
    auto alloc = [&](size_t bytes) {
        char* r = p;
        p += (bytes + 255) & ~(size_t)255;
        return r;
    };
    _Float16* xph   = (_Float16*)alloc((size_t)n * HD * 2);
    _Float16* Wh    = (_Float16*)alloc((size_t)HD * IN_DIM * 2);
    float* s_src    = (float*)alloc((size_t)n * 4 * 4);
    float* s_dst    = (float*)alloc((size_t)n * 4 * 4);
    float* att_csr  = (float*)alloc((size_t)EP * 4 * 4);
    float* weff     = (float*)alloc(128 * 4);
    int*   deg      = (int*)alloc((size_t)n * 4);
    int*   rowptr   = (int*)alloc((size_t)(n + 1) * 4);
    int*   cursor   = (int*)alloc((size_t)n * 4);
    int*   ssrc     = (int*)alloc((size_t)EP * 4);
    int*   flag     = (int*)alloc(4);

    prep_kernel<<<2 + WCVT_BLOCKS + (n + 255) / 256, 256, 0, stream>>>(
        ei, lin_eW, att_edge, lin_W, weff, Wh, deg, flag, n);
    deg_kernel<<<(E + 255) / 256, 256, 0, stream>>>(ei, flag, deg, E);
    proj_kernel<<<(n + 15) / 16, 256, 0, stream>>>(x, Wh, att_src, att_dst, xph,
                                                   s_src, s_dst, n);
    scan_kernel<<<1, SCAN_T, 0, stream>>>(deg, rowptr, cursor, n);
    scatter_kernel<<<(EP + 255) / 256, 256, 0, stream>>>(ei, ea, s_src, s_dst, weff, flag,
                                                         cursor, ssrc, att_csr, E, n);
    agg_kernel<<<(n + 3) / 4, 256, 0, stream>>>(rowptr, ssrc, att_csr, xph, bias, out, n);
}

// Round 5
// 128.642 us; speedup vs baseline: 1.7252x; 1.1829x over previous
//
#include <hip/hip_runtime.h>
#include <math.h>

#define IN_DIM 256
#define HD 256
#define EDGE_DIM 32
#define NEG_SLOPE 0.2f
#define CAP 128
#define PSTRIDE 136

typedef _Float16 f16x8 __attribute__((ext_vector_type(8)));
typedef _Float16 f16x4 __attribute__((ext_vector_type(4)));
typedef float f32x4 __attribute__((ext_vector_type(4)));

__device__ __forceinline__ void load_edge(const int* ei, int e, int E, int n, int is64,
                                          int& s, int& d) {
    if (e < E) {
        if (is64) { s = ei[2 * e]; d = ei[2 * E + 2 * e]; }
        else      { s = ei[e];     d = ei[E + e]; }
    } else {
        s = d = e - E;  // self loop
    }
}

__device__ __forceinline__ f16x8 cvt8(const float* p) {
    float4 lo = *(const float4*)p;
    float4 hi = *(const float4*)(p + 4);
    auto a = __builtin_amdgcn_cvt_pkrtz(lo.x, lo.y);
    auto b = __builtin_amdgcn_cvt_pkrtz(lo.z, lo.w);
    auto c = __builtin_amdgcn_cvt_pkrtz(hi.x, hi.y);
    auto d = __builtin_amdgcn_cvt_pkrtz(hi.z, hi.w);
    f16x8 r;
    r[0] = (_Float16)a[0]; r[1] = (_Float16)a[1];
    r[2] = (_Float16)b[0]; r[3] = (_Float16)b[1];
    r[4] = (_Float16)c[0]; r[5] = (_Float16)c[1];
    r[6] = (_Float16)d[0]; r[7] = (_Float16)d[1];
    return r;
}

// ---------- prep: weff (b0), detect (b1), W->fp16 (b2..33), deg histogram (b34..) ----------
// deg[] must be zeroed before this kernel (hipMemsetAsync). Histogram blocks do their own
// int64-detect (can't rely on block 1's flag within the same kernel).
#define WCVT_BLOCKS 32
__global__ __launch_bounds__(256) void prep_kernel(const int* __restrict__ ei,
                                                   const float* __restrict__ lew,
                                                   const float* __restrict__ ae,
                                                   const float* __restrict__ W,
                                                   float* __restrict__ weff,
                                                   _Float16* __restrict__ Wh,
                                                   int* __restrict__ deg,
                                                   int* __restrict__ flag, int E, int n) {
    int b = blockIdx.x;
    int t = threadIdx.x;
    if (b == 0) {
        if (t < 128) {
            int h = t >> 5, k = t & 31;
            float s = 0.f;
#pragma unroll 8
            for (int d = 0; d < 64; ++d) s += lew[(h * 64 + d) * 32 + k] * ae[h * 64 + d];
            weff[t] = s;
        }
    } else if (b == 1) {
        __shared__ int anynz;
        if (t == 0) anynz = 0;
        __syncthreads();
        if (ei[2 * t + 1] != 0) atomicOr(&anynz, 1);
        __syncthreads();
        if (t == 0) *flag = (anynz == 0) ? 1 : 0;
    } else if (b < 2 + WCVT_BLOCKS) {
        int idx = (b - 2) * 2048 + t * 8;
        *(f16x8*)&Wh[idx] = cvt8(&W[idx]);
    } else {
        // degree histogram, 4 edges per thread, block-local detect
        __shared__ int anynz;
        if (t == 0) anynz = 0;
        __syncthreads();
        if (ei[2 * t + 1] != 0) atomicOr(&anynz, 1);
        __syncthreads();
        int is64 = (anynz == 0);
        int e0 = ((b - 2 - WCVT_BLOCKS) * 256 + t) * 4;
        if (e0 >= E) return;
        if (!is64) {
            if (e0 + 4 <= E && (E & 3) == 0) {
                int4 d4 = *(const int4*)&ei[E + e0];
                atomicAdd(&deg[d4.x], 1); atomicAdd(&deg[d4.y], 1);
                atomicAdd(&deg[d4.z], 1); atomicAdd(&deg[d4.w], 1);
            } else {
                for (int e = e0; e < E && e < e0 + 4; ++e) atomicAdd(&deg[ei[E + e]], 1);
            }
        } else {
            if (e0 + 4 <= E) {
                int4 a = *(const int4*)&ei[2 * E + 2 * e0];
                int4 b4 = *(const int4*)&ei[2 * E + 2 * e0 + 4];
                atomicAdd(&deg[a.x], 1); atomicAdd(&deg[a.z], 1);
                atomicAdd(&deg[b4.x], 1); atomicAdd(&deg[b4.z], 1);
            } else {
                for (int e = e0; e < E && e < e0 + 4; ++e)
                    atomicAdd(&deg[ei[2 * E + 2 * e]], 1);
            }
        }
    }
}

// ---------- x_proj (fp16) via MFMA, 16 rows/block, fused s_src/s_dst epilogue ----------
__global__ __launch_bounds__(256) void proj_kernel(const float* __restrict__ x,
                                                   const _Float16* __restrict__ Wh,
                                                   const float* __restrict__ asrc_g,
                                                   const float* __restrict__ adst_g,
                                                   _Float16* __restrict__ xph,
                                                   float* __restrict__ s_src,
                                                   float* __restrict__ s_dst, int n) {
    int tid = threadIdx.x;
    int lane = tid & 63;
    int w = tid >> 6;            // wave id == head id (col group)
    int m0 = blockIdx.x * 16;
    int c0 = w * 64;
    int r = lane & 15;
    int kq = lane >> 4;          // 0..3

    float asr[4], ads[4];
#pragma unroll
    for (int ci = 0; ci < 4; ++ci) {
        asr[ci] = asrc_g[c0 + ci * 16 + r];
        ads[ci] = adst_g[c0 + ci * 16 + r];
    }

    f32x4 acc[4];
#pragma unroll
    for (int j = 0; j < 4; ++j) acc[j] = (f32x4){0.f, 0.f, 0.f, 0.f};

    int row = m0 + r;
    bool rok = row < n;
#pragma unroll
    for (int k0 = 0; k0 < IN_DIM; k0 += 32) {
        int kk = k0 + kq * 8;
        f16x8 a = {0, 0, 0, 0, 0, 0, 0, 0};
        if (rok) a = cvt8(&x[(size_t)row * IN_DIM + kk]);
        f16x8 bfr[4];
#pragma unroll
        for (int ci = 0; ci < 4; ++ci)
            bfr[ci] = *(const f16x8*)&Wh[(size_t)(c0 + ci * 16 + r) * IN_DIM + kk];
#pragma unroll
        for (int ci = 0; ci < 4; ++ci)
            acc[ci] = __builtin_amdgcn_mfma_f32_16x16x32_f16(a, bfr[ci], acc[ci], 0, 0, 0);
    }
    // C/D layout: col = lane&15, row = (lane>>4)*4 + j
#pragma unroll
    for (int j = 0; j < 4; ++j) {
        int orow = m0 + kq * 4 + j;
        if (orow < n) {
#pragma unroll
            for (int ci = 0; ci < 4; ++ci)
                xph[(size_t)orow * HD + c0 + ci * 16 + r] = (_Float16)acc[ci][j];
        }
    }
    // fused attention scores: wave w == head w owns cols [w*64, w*64+64)
#pragma unroll
    for (int j = 0; j < 4; ++j) {
        float vs = 0.f, vd = 0.f;
#pragma unroll
        for (int ci = 0; ci < 4; ++ci) {
            vs += acc[ci][j] * asr[ci];
            vd += acc[ci][j] * ads[ci];
        }
#pragma unroll
        for (int msk = 1; msk < 16; msk <<= 1) {
            vs += __shfl_xor(vs, msk);
            vd += __shfl_xor(vd, msk);
        }
        int orow = m0 + kq * 4 + j;
        if (r == 0 && orow < n) {
            s_src[orow * 4 + w] = vs;
            s_dst[orow * 4 + w] = vd;
        }
    }
}

// ---------- single-block exclusive scan over (deg+1), int4-vectorized ----------
#define SCAN_T 1024
__global__ __launch_bounds__(SCAN_T) void scan_kernel(const int* __restrict__ deg,
                                                      int* __restrict__ rowptr,
                                                      int* __restrict__ cursor, int n) {
    __shared__ int sdata[SCAN_T];
    int t = threadIdx.x;
    int per = (n + SCAN_T - 1) / SCAN_T;
    int begin = t * per;
    int endi = begin + per;
    if (endi > n) endi = n;
    if (begin > n) begin = n;
    bool vec = ((begin & 3) == 0) && (((endi - begin) & 3) == 0);
    int s = 0;
    if (vec) {
        for (int i = begin; i < endi; i += 4) {
            int4 v = *(const int4*)&deg[i];
            s += v.x + v.y + v.z + v.w + 4;
        }
    } else {
        for (int i = begin; i < endi; ++i) s += deg[i] + 1;
    }
    sdata[t] = s;
    __syncthreads();
    for (int off = 1; off < SCAN_T; off <<= 1) {
        int v = 0;
        if (t >= off) v = sdata[t - off];
        __syncthreads();
        sdata[t] += v;
        __syncthreads();
    }
    int run = (t == 0) ? 0 : sdata[t - 1];
    if (vec) {
        for (int i = begin; i < endi; i += 4) {
            int4 v = *(const int4*)&deg[i];
            int4 o;
            o.x = run; run += v.x + 1;
            o.y = run; run += v.y + 1;
            o.z = run; run += v.z + 1;
            o.w = run; run += v.w + 1;
            *(int4*)&rowptr[i] = o;
            *(int4*)&cursor[i] = o;
        }
    } else {
        for (int i = begin; i < endi; ++i) {
            int dv = deg[i] + 1;
            rowptr[i] = run;
            cursor[i] = run;
            run += dv;
        }
    }
    if (t == SCAN_T - 1) rowptr[n] = run;
}

// ---------- fused edge scoring + exp + CSR scatter (no max subtraction) ----------
__global__ __launch_bounds__(256) void scatter_kernel(const int* __restrict__ ei,
                                                      const float* __restrict__ ea,
                                                      const float* __restrict__ s_src,
                                                      const float* __restrict__ s_dst,
                                                      const float* __restrict__ weff,
                                                      const int* __restrict__ flag,
                                                      int* __restrict__ cursor,
                                                      int* __restrict__ ssrc,
                                                      float* __restrict__ p_csr,
                                                      int E, int n) {
    __shared__ float we[128];
    if (threadIdx.x < 128) we[threadIdx.x] = weff[threadIdx.x];
    __syncthreads();
    int e = blockIdx.x * blockDim.x + threadIdx.x;
    int EP = E + n;
    if (e >= EP) return;
    int is64 = *flag;
    int s, d;
    load_edge(ei, e, E, n, is64, s, d);
    float4 vs = *(const float4*)&s_src[(size_t)s * 4];
    float4 vd = *(const float4*)&s_dst[(size_t)d * 4];
    float ed[4] = {0.f, 0.f, 0.f, 0.f};
    if (e < E) {
#pragma unroll
        for (int k = 0; k < EDGE_DIM; k += 4) {
            float4 v = *(const float4*)&ea[(size_t)e * EDGE_DIM + k];
#pragma unroll
            for (int h = 0; h < 4; ++h) {
                ed[h] += v.x * we[h * 32 + k + 0] + v.y * we[h * 32 + k + 1] +
                         v.z * we[h * 32 + k + 2] + v.w * we[h * 32 + k + 3];
            }
        }
    }
    float t0 = vs.x + vd.x + ed[0];
    float t1 = vs.y + vd.y + ed[1];
    float t2 = vs.z + vd.z + ed[2];
    float t3 = vs.w + vd.w + ed[3];
    t0 = t0 >= 0.f ? t0 : NEG_SLOPE * t0;
    t1 = t1 >= 0.f ? t1 : NEG_SLOPE * t1;
    t2 = t2 >= 0.f ? t2 : NEG_SLOPE * t2;
    t3 = t3 >= 0.f ? t3 : NEG_SLOPE * t3;
    float4 o;
    o.x = __expf(t0);
    o.y = __expf(t1);
    o.z = __expf(t2);
    o.w = __expf(t3);
    int pos = atomicAdd(&cursor[d], 1);
    ssrc[pos] = s;
    *(float4*)&p_csr[(size_t)pos * 4] = o;
}

// ---------- softmax + aggregation: one wave per node, 2 passes, LDS-cached p ----------
__global__ __launch_bounds__(256) void agg_kernel(const int* __restrict__ rowptr,
                                                  const int* __restrict__ ssrc,
                                                  const float* __restrict__ p_csr,
                                                  const _Float16* __restrict__ xph,
                                                  const float* __restrict__ bias,
                                                  float* __restrict__ out, int n) {
    __shared__ float pl[4][4 * PSTRIDE];
    int wv = threadIdx.x >> 6;
    float* pbuf = pl[wv];
    int wid = (blockIdx.x * blockDim.x + threadIdx.x) >> 6;
    int lane = threadIdx.x & 63;
    if (wid >= n) return;
    int start = rowptr[wid];
    int end = rowptr[wid + 1];
    int deg = end - start;

    float d0 = 0.f, d1 = 0.f, d2 = 0.f, d3 = 0.f;
    for (int i = start + lane; i < end; i += 64) {
        float4 a = *(const float4*)&p_csr[(size_t)i * 4];
        int idx = i - start;
        if (idx < CAP) {
            pbuf[0 * PSTRIDE + idx] = a.x;
            pbuf[1 * PSTRIDE + idx] = a.y;
            pbuf[2 * PSTRIDE + idx] = a.z;
            pbuf[3 * PSTRIDE + idx] = a.w;
        }
        d0 += a.x; d1 += a.y; d2 += a.z; d3 += a.w;
    }
#pragma unroll
    for (int o = 1; o < 64; o <<= 1) {
        d0 += __shfl_xor(d0, o);
        d1 += __shfl_xor(d1, o);
        d2 += __shfl_xor(d2, o);
        d3 += __shfl_xor(d3, o);
    }
    int h = lane >> 4;
    float dh = h == 0 ? d0 : (h == 1 ? d1 : (h == 2 ? d2 : d3));
    float invh = 1.f / (dh + 1e-12f);
    const float* ph = &pbuf[h * PSTRIDE];

    float ax = 0.f, ay = 0.f, az = 0.f, aw = 0.f;
    int idx = 0;
    for (; idx + 2 <= deg; idx += 2) {
        int s0 = ssrc[start + idx];
        int s1 = ssrc[start + idx + 1];
        float p0 = (idx < CAP) ? ph[idx] : p_csr[(size_t)(start + idx) * 4 + h];
        float p1 = (idx + 1 < CAP) ? ph[idx + 1] : p_csr[(size_t)(start + idx + 1) * 4 + h];
        f16x4 x0 = *(const f16x4*)&xph[(size_t)s0 * HD + lane * 4];
        f16x4 x1 = *(const f16x4*)&xph[(size_t)s1 * HD + lane * 4];
        float al0 = p0 * invh;
        float al1 = p1 * invh;
        ax += al0 * (float)x0[0] + al1 * (float)x1[0];
        ay += al0 * (float)x0[1] + al1 * (float)x1[1];
        az += al0 * (float)x0[2] + al1 * (float)x1[2];
        aw += al0 * (float)x0[3] + al1 * (float)x1[3];
    }
    if (idx < deg) {
        int s0 = ssrc[start + idx];
        float p0 = (idx < CAP) ? ph[idx] : p_csr[(size_t)(start + idx) * 4 + h];
        f16x4 x0 = *(const f16x4*)&xph[(size_t)s0 * HD + lane * 4];
        float al0 = p0 * invh;
        ax += al0 * (float)x0[0];
        ay += al0 * (float)x0[1];
        az += al0 * (float)x0[2];
        aw += al0 * (float)x0[3];
    }
    float4 b = *(const float4*)&bias[lane * 4];
    float4 o4;
    o4.x = ax + b.x; o4.y = ay + b.y; o4.z = az + b.z; o4.w = aw + b.w;
    *(float4*)&out[(size_t)wid * HD + lane * 4] = o4;
}

extern "C" void kernel_launch(void* const* d_in, const int* in_sizes, int n_in,
                              void* d_out, int out_size, void* d_ws, size_t ws_size,
                              hipStream_t stream) {
    const float* x        = (const float*)d_in[0];
    const int*   ei       = (const int*)d_in[1];
    const float* ea       = (const float*)d_in[2];
    const float* lin_W    = (const float*)d_in[3];
    const float* att_src  = (const float*)d_in[4];
    const float* att_dst  = (const float*)d_in[5];
    const float* lin_eW   = (const float*)d_in[6];
    const float* att_edge = (const float*)d_in[7];
    const float* bias     = (const float*)d_in[8];
    float* out = (float*)d_out;

    int n  = in_sizes[0] / IN_DIM;     // 20000
    int E  = in_sizes[2] / EDGE_DIM;   // 320000
    int EP = E + n;

    char* p = (char*)d_ws;
    auto alloc = [&](size_t bytes) {
        char* r = p;
        p += (bytes + 255) & ~(size_t)255;
        return r;
    };
    _Float16* xph   = (_Float16*)alloc((size_t)n * HD * 2);
    _Float16* Wh    = (_Float16*)alloc((size_t)HD * IN_DIM * 2);
    float* s_src    = (float*)alloc((size_t)n * 4 * 4);
    float* s_dst    = (float*)alloc((size_t)n * 4 * 4);
    float* p_csr    = (float*)alloc((size_t)EP * 4 * 4);
    float* weff     = (float*)alloc(128 * 4);
    int*   deg      = (int*)alloc((size_t)n * 4);
    int*   rowptr   = (int*)alloc((size_t)(n + 1) * 4);
    int*   cursor   = (int*)alloc((size_t)n * 4);
    int*   ssrc     = (int*)alloc((size_t)EP * 4);
    int*   flag     = (int*)alloc(4);

    hipMemsetAsync(deg, 0, (size_t)n * 4, stream);
    int hist_blocks = (E + 1023) / 1024;
    prep_kernel<<<2 + WCVT_BLOCKS + hist_blocks, 256, 0, stream>>>(
        ei, lin_eW, att_edge, lin_W, weff, Wh, deg, flag, E, n);
    proj_kernel<<<(n + 15) / 16, 256, 0, stream>>>(x, Wh, att_src, att_dst, xph,
                                                   s_src, s_dst, n);
    scan_kernel<<<1, SCAN_T, 0, stream>>>(deg, rowptr, cursor, n);
    scatter_kernel<<<(EP + 255) / 256, 256, 0, stream>>>(ei, ea, s_src, s_dst, weff, flag,
                                                         cursor, ssrc, p_csr, E, n);
    agg_kernel<<<(n + 3) / 4, 256, 0, stream>>>(rowptr, ssrc, p_csr, xph, bias, out, n);
}

// Round 6
// 119.822 us; speedup vs baseline: 1.8522x; 1.0736x over previous
//
#include <hip/hip_runtime.h>
#include <math.h>

#define IN_DIM 256
#define HD 256
#define EDGE_DIM 32
#define NEG_SLOPE 0.2f
#define CAP 128
#define PSTRIDE 136

typedef _Float16 f16x8 __attribute__((ext_vector_type(8)));
typedef _Float16 f16x4 __attribute__((ext_vector_type(4)));
typedef float f32x4 __attribute__((ext_vector_type(4)));

__device__ __forceinline__ void load_edge(const int* ei, int e, int E, int n, int is64,
                                          int& s, int& d) {
    if (e < E) {
        if (is64) { s = ei[2 * e]; d = ei[2 * E + 2 * e]; }
        else      { s = ei[e];     d = ei[E + e]; }
    } else {
        s = d = e - E;  // self loop
    }
}

__device__ __forceinline__ f16x8 cvt8(const float* p) {
    float4 lo = *(const float4*)p;
    float4 hi = *(const float4*)(p + 4);
    auto a = __builtin_amdgcn_cvt_pkrtz(lo.x, lo.y);
    auto b = __builtin_amdgcn_cvt_pkrtz(lo.z, lo.w);
    auto c = __builtin_amdgcn_cvt_pkrtz(hi.x, hi.y);
    auto d = __builtin_amdgcn_cvt_pkrtz(hi.z, hi.w);
    f16x8 r;
    r[0] = (_Float16)a[0]; r[1] = (_Float16)a[1];
    r[2] = (_Float16)b[0]; r[3] = (_Float16)b[1];
    r[4] = (_Float16)c[0]; r[5] = (_Float16)c[1];
    r[6] = (_Float16)d[0]; r[7] = (_Float16)d[1];
    return r;
}

// ---------- prep: weff (b0), detect (b1), W->fp16 (b2..33), deg histogram + perm (b34..) ----
// deg[] must be zeroed before this kernel (hipMemsetAsync). Histogram blocks do their own
// int64-detect. perm[e] = within-bucket ordinal of edge e (histogram atomic's return).
#define WCVT_BLOCKS 32
__global__ __launch_bounds__(256) void prep_kernel(const int* __restrict__ ei,
                                                   const float* __restrict__ lew,
                                                   const float* __restrict__ ae,
                                                   const float* __restrict__ W,
                                                   float* __restrict__ weff,
                                                   _Float16* __restrict__ Wh,
                                                   int* __restrict__ deg,
                                                   int* __restrict__ perm,
                                                   int* __restrict__ flag, int E, int n) {
    int b = blockIdx.x;
    int t = threadIdx.x;
    if (b == 0) {
        if (t < 128) {
            int h = t >> 5, k = t & 31;
            float s = 0.f;
#pragma unroll 8
            for (int d = 0; d < 64; ++d) s += lew[(h * 64 + d) * 32 + k] * ae[h * 64 + d];
            weff[t] = s;
        }
    } else if (b == 1) {
        __shared__ int anynz;
        if (t == 0) anynz = 0;
        __syncthreads();
        if (ei[2 * t + 1] != 0) atomicOr(&anynz, 1);
        __syncthreads();
        if (t == 0) *flag = (anynz == 0) ? 1 : 0;
    } else if (b < 2 + WCVT_BLOCKS) {
        int idx = (b - 2) * 2048 + t * 8;
        *(f16x8*)&Wh[idx] = cvt8(&W[idx]);
    } else {
        // degree histogram + perm, 4 edges per thread, block-local detect
        __shared__ int anynz;
        if (t == 0) anynz = 0;
        __syncthreads();
        if (ei[2 * t + 1] != 0) atomicOr(&anynz, 1);
        __syncthreads();
        int is64 = (anynz == 0);
        int e0 = ((b - 2 - WCVT_BLOCKS) * 256 + t) * 4;
        if (e0 >= E) return;
        if (e0 + 4 <= E) {
            int4 pm;
            if (!is64) {
                int4 d4 = *(const int4*)&ei[E + e0];
                pm.x = atomicAdd(&deg[d4.x], 1);
                pm.y = atomicAdd(&deg[d4.y], 1);
                pm.z = atomicAdd(&deg[d4.z], 1);
                pm.w = atomicAdd(&deg[d4.w], 1);
            } else {
                int4 a = *(const int4*)&ei[2 * E + 2 * e0];
                int4 b4 = *(const int4*)&ei[2 * E + 2 * e0 + 4];
                pm.x = atomicAdd(&deg[a.x], 1);
                pm.y = atomicAdd(&deg[a.z], 1);
                pm.z = atomicAdd(&deg[b4.x], 1);
                pm.w = atomicAdd(&deg[b4.z], 1);
            }
            *(int4*)&perm[e0] = pm;
        } else {
            for (int e = e0; e < E && e < e0 + 4; ++e) {
                int d = is64 ? ei[2 * E + 2 * e] : ei[E + e];
                perm[e] = atomicAdd(&deg[d], 1);
            }
        }
    }
}

// ---------- x_proj (fp16) via MFMA, 16 rows/block, fused s_src/s_dst epilogue ----------
__global__ __launch_bounds__(256) void proj_kernel(const float* __restrict__ x,
                                                   const _Float16* __restrict__ Wh,
                                                   const float* __restrict__ asrc_g,
                                                   const float* __restrict__ adst_g,
                                                   _Float16* __restrict__ xph,
                                                   float* __restrict__ s_src,
                                                   float* __restrict__ s_dst, int n) {
    int tid = threadIdx.x;
    int lane = tid & 63;
    int w = tid >> 6;            // wave id == head id (col group)
    int m0 = blockIdx.x * 16;
    int c0 = w * 64;
    int r = lane & 15;
    int kq = lane >> 4;          // 0..3

    float asr[4], ads[4];
#pragma unroll
    for (int ci = 0; ci < 4; ++ci) {
        asr[ci] = asrc_g[c0 + ci * 16 + r];
        ads[ci] = adst_g[c0 + ci * 16 + r];
    }

    f32x4 acc[4];
#pragma unroll
    for (int j = 0; j < 4; ++j) acc[j] = (f32x4){0.f, 0.f, 0.f, 0.f};

    int row = m0 + r;
    bool rok = row < n;
#pragma unroll
    for (int k0 = 0; k0 < IN_DIM; k0 += 32) {
        int kk = k0 + kq * 8;
        f16x8 a = {0, 0, 0, 0, 0, 0, 0, 0};
        if (rok) a = cvt8(&x[(size_t)row * IN_DIM + kk]);
        f16x8 bfr[4];
#pragma unroll
        for (int ci = 0; ci < 4; ++ci)
            bfr[ci] = *(const f16x8*)&Wh[(size_t)(c0 + ci * 16 + r) * IN_DIM + kk];
#pragma unroll
        for (int ci = 0; ci < 4; ++ci)
            acc[ci] = __builtin_amdgcn_mfma_f32_16x16x32_f16(a, bfr[ci], acc[ci], 0, 0, 0);
    }
    // C/D layout: col = lane&15, row = (lane>>4)*4 + j
#pragma unroll
    for (int j = 0; j < 4; ++j) {
        int orow = m0 + kq * 4 + j;
        if (orow < n) {
#pragma unroll
            for (int ci = 0; ci < 4; ++ci)
                xph[(size_t)orow * HD + c0 + ci * 16 + r] = (_Float16)acc[ci][j];
        }
    }
    // fused attention scores: wave w == head w owns cols [w*64, w*64+64)
#pragma unroll
    for (int j = 0; j < 4; ++j) {
        float vs = 0.f, vd = 0.f;
#pragma unroll
        for (int ci = 0; ci < 4; ++ci) {
            vs += acc[ci][j] * asr[ci];
            vd += acc[ci][j] * ads[ci];
        }
#pragma unroll
        for (int msk = 1; msk < 16; msk <<= 1) {
            vs += __shfl_xor(vs, msk);
            vd += __shfl_xor(vd, msk);
        }
        int orow = m0 + kq * 4 + j;
        if (r == 0 && orow < n) {
            s_src[orow * 4 + w] = vs;
            s_dst[orow * 4 + w] = vd;
        }
    }
}

// ---------- single-block exclusive scan over (deg+1), int4-vectorized ----------
#define SCAN_T 1024
__global__ __launch_bounds__(SCAN_T) void scan_kernel(const int* __restrict__ deg,
                                                      int* __restrict__ rowptr, int n) {
    __shared__ int sdata[SCAN_T];
    int t = threadIdx.x;
    int per = (n + SCAN_T - 1) / SCAN_T;
    int begin = t * per;
    int endi = begin + per;
    if (endi > n) endi = n;
    if (begin > n) begin = n;
    bool vec = ((begin & 3) == 0) && (((endi - begin) & 3) == 0);
    int s = 0;
    if (vec) {
        for (int i = begin; i < endi; i += 4) {
            int4 v = *(const int4*)&deg[i];
            s += v.x + v.y + v.z + v.w + 4;
        }
    } else {
        for (int i = begin; i < endi; ++i) s += deg[i] + 1;
    }
    sdata[t] = s;
    __syncthreads();
    for (int off = 1; off < SCAN_T; off <<= 1) {
        int v = 0;
        if (t >= off) v = sdata[t - off];
        __syncthreads();
        sdata[t] += v;
        __syncthreads();
    }
    int run = (t == 0) ? 0 : sdata[t - 1];
    if (vec) {
        for (int i = begin; i < endi; i += 4) {
            int4 v = *(const int4*)&deg[i];
            int4 o;
            o.x = run; run += v.x + 1;
            o.y = run; run += v.y + 1;
            o.z = run; run += v.z + 1;
            o.w = run; run += v.w + 1;
            *(int4*)&rowptr[i] = o;
        }
    } else {
        for (int i = begin; i < endi; ++i) {
            rowptr[i] = run;
            run += deg[i] + 1;
        }
    }
    if (t == SCAN_T - 1) rowptr[n] = run;
}

// ---------- edge scoring + exp + CSR placement (atomic-free) ----------
__global__ __launch_bounds__(256) void edge_kernel(const int* __restrict__ ei,
                                                   const float* __restrict__ ea,
                                                   const float* __restrict__ s_src,
                                                   const float* __restrict__ s_dst,
                                                   const float* __restrict__ weff,
                                                   const int* __restrict__ flag,
                                                   const int* __restrict__ rowptr,
                                                   const int* __restrict__ perm,
                                                   int* __restrict__ src_csr,
                                                   float* __restrict__ p_csr,
                                                   int E, int n) {
    __shared__ float we[128];
    if (threadIdx.x < 128) we[threadIdx.x] = weff[threadIdx.x];
    __syncthreads();
    int e = blockIdx.x * blockDim.x + threadIdx.x;
    int EP = E + n;
    if (e >= EP) return;
    int is64 = *flag;
    int s, d;
    load_edge(ei, e, E, n, is64, s, d);
    int pos;
    if (e < E) pos = rowptr[d] + perm[e];
    else       pos = rowptr[d + 1] - 1;   // self-loop takes last slot of bucket
    float4 vs = *(const float4*)&s_src[(size_t)s * 4];
    float4 vd = *(const float4*)&s_dst[(size_t)d * 4];
    float ed[4] = {0.f, 0.f, 0.f, 0.f};
    if (e < E) {
#pragma unroll
        for (int k = 0; k < EDGE_DIM; k += 4) {
            float4 v = *(const float4*)&ea[(size_t)e * EDGE_DIM + k];
#pragma unroll
            for (int h = 0; h < 4; ++h) {
                ed[h] += v.x * we[h * 32 + k + 0] + v.y * we[h * 32 + k + 1] +
                         v.z * we[h * 32 + k + 2] + v.w * we[h * 32 + k + 3];
            }
        }
    }
    float t0 = vs.x + vd.x + ed[0];
    float t1 = vs.y + vd.y + ed[1];
    float t2 = vs.z + vd.z + ed[2];
    float t3 = vs.w + vd.w + ed[3];
    t0 = t0 >= 0.f ? t0 : NEG_SLOPE * t0;
    t1 = t1 >= 0.f ? t1 : NEG_SLOPE * t1;
    t2 = t2 >= 0.f ? t2 : NEG_SLOPE * t2;
    t3 = t3 >= 0.f ? t3 : NEG_SLOPE * t3;
    float4 o;
    o.x = __expf(t0);
    o.y = __expf(t1);
    o.z = __expf(t2);
    o.w = __expf(t3);
    src_csr[pos] = s;
    *(float4*)&p_csr[(size_t)pos * 4] = o;
}

// ---------- softmax + aggregation: one wave per node, 2 passes, LDS-cached p ----------
__global__ __launch_bounds__(256) void agg_kernel(const int* __restrict__ rowptr,
                                                  const int* __restrict__ src_csr,
                                                  const float* __restrict__ p_csr,
                                                  const _Float16* __restrict__ xph,
                                                  const float* __restrict__ bias,
                                                  float* __restrict__ out, int n) {
    __shared__ float pl[4][4 * PSTRIDE];
    int wv = threadIdx.x >> 6;
    float* pbuf = pl[wv];
    int wid = (blockIdx.x * blockDim.x + threadIdx.x) >> 6;
    int lane = threadIdx.x & 63;
    if (wid >= n) return;
    int start = rowptr[wid];
    int end = rowptr[wid + 1];
    int deg = end - start;

    float d0 = 0.f, d1 = 0.f, d2 = 0.f, d3 = 0.f;
    for (int i = start + lane; i < end; i += 64) {
        float4 a = *(const float4*)&p_csr[(size_t)i * 4];
        int idx = i - start;
        if (idx < CAP) {
            pbuf[0 * PSTRIDE + idx] = a.x;
            pbuf[1 * PSTRIDE + idx] = a.y;
            pbuf[2 * PSTRIDE + idx] = a.z;
            pbuf[3 * PSTRIDE + idx] = a.w;
        }
        d0 += a.x; d1 += a.y; d2 += a.z; d3 += a.w;
    }
#pragma unroll
    for (int o = 1; o < 64; o <<= 1) {
        d0 += __shfl_xor(d0, o);
        d1 += __shfl_xor(d1, o);
        d2 += __shfl_xor(d2, o);
        d3 += __shfl_xor(d3, o);
    }
    int h = lane >> 4;
    float dh = h == 0 ? d0 : (h == 1 ? d1 : (h == 2 ? d2 : d3));
    float invh = 1.f / (dh + 1e-12f);
    const float* ph = &pbuf[h * PSTRIDE];

    float ax = 0.f, ay = 0.f, az = 0.f, aw = 0.f;
    int idx = 0;
    for (; idx + 2 <= deg; idx += 2) {
        int s0 = src_csr[start + idx];
        int s1 = src_csr[start + idx + 1];
        float p0 = (idx < CAP) ? ph[idx] : p_csr[(size_t)(start + idx) * 4 + h];
        float p1 = (idx + 1 < CAP) ? ph[idx + 1] : p_csr[(size_t)(start + idx + 1) * 4 + h];
        f16x4 x0 = *(const f16x4*)&xph[(size_t)s0 * HD + lane * 4];
        f16x4 x1 = *(const f16x4*)&xph[(size_t)s1 * HD + lane * 4];
        float al0 = p0 * invh;
        float al1 = p1 * invh;
        ax += al0 * (float)x0[0] + al1 * (float)x1[0];
        ay += al0 * (float)x0[1] + al1 * (float)x1[1];
        az += al0 * (float)x0[2] + al1 * (float)x1[2];
        aw += al0 * (float)x0[3] + al1 * (float)x1[3];
    }
    if (idx < deg) {
        int s0 = src_csr[start + idx];
        float p0 = (idx < CAP) ? ph[idx] : p_csr[(size_t)(start + idx) * 4 + h];
        f16x4 x0 = *(const f16x4*)&xph[(size_t)s0 * HD + lane * 4];
        float al0 = p0 * invh;
        ax += al0 * (float)x0[0];
        ay += al0 * (float)x0[1];
        az += al0 * (float)x0[2];
        aw += al0 * (float)x0[3];
    }
    float4 b = *(const float4*)&bias[lane * 4];
    float4 o4;
    o4.x = ax + b.x; o4.y = ay + b.y; o4.z = az + b.z; o4.w = aw + b.w;
    *(float4*)&out[(size_t)wid * HD + lane * 4] = o4;
}

extern "C" void kernel_launch(void* const* d_in, const int* in_sizes, int n_in,
                              void* d_out, int out_size, void* d_ws, size_t ws_size,
                              hipStream_t stream) {
    const float* x        = (const float*)d_in[0];
    const int*   ei       = (const int*)d_in[1];
    const float* ea       = (const float*)d_in[2];
    const float* lin_W    = (const float*)d_in[3];
    const float* att_src  = (const float*)d_in[4];
    const float* att_dst  = (const float*)d_in[5];
    const float* lin_eW   = (const float*)d_in[6];
    const float* att_edge = (const float*)d_in[7];
    const float* bias     = (const float*)d_in[8];
    float* out = (float*)d_out;

    int n  = in_sizes[0] / IN_DIM;     // 20000
    int E  = in_sizes[2] / EDGE_DIM;   // 320000
    int EP = E + n;

    char* p = (char*)d_ws;
    auto alloc = [&](size_t bytes) {
        char* r = p;
        p += (bytes + 255) & ~(size_t)255;
        return r;
    };
    _Float16* xph   = (_Float16*)alloc((size_t)n * HD * 2);
    _Float16* Wh    = (_Float16*)alloc((size_t)HD * IN_DIM * 2);
    float* s_src    = (float*)alloc((size_t)n * 4 * 4);
    float* s_dst    = (float*)alloc((size_t)n * 4 * 4);
    float* p_csr    = (float*)alloc((size_t)EP * 4 * 4);
    float* weff     = (float*)alloc(128 * 4);
    int*   deg      = (int*)alloc((size_t)n * 4);
    int*   rowptr   = (int*)alloc((size_t)(n + 1) * 4);
    int*   perm     = (int*)alloc((size_t)E * 4);
    int*   src_csr  = (int*)alloc((size_t)EP * 4);
    int*   flag     = (int*)alloc(4);

    hipMemsetAsync(deg, 0, (size_t)n * 4, stream);
    int hist_blocks = (E + 1023) / 1024;
    prep_kernel<<<2 + WCVT_BLOCKS + hist_blocks, 256, 0, stream>>>(
        ei, lin_eW, att_edge, lin_W, weff, Wh, deg, perm, flag, E, n);
    proj_kernel<<<(n + 15) / 16, 256, 0, stream>>>(x, Wh, att_src, att_dst, xph,
                                                   s_src, s_dst, n);
    scan_kernel<<<1, SCAN_T, 0, stream>>>(deg, rowptr, n);
    edge_kernel<<<(EP + 255) / 256, 256, 0, stream>>>(ei, ea, s_src, s_dst, weff, flag,
                                                      rowptr, perm, src_csr, p_csr, E, n);
    agg_kernel<<<(n + 3) / 4, 256, 0, stream>>>(rowptr, src_csr, p_csr, xph, bias, out, n);
}